// Round 8
// baseline (556.859 us; speedup 1.0000x reference)
//
#include <hip/hip_runtime.h>
#include <hip/hip_bf16.h>
#include <cstdint>
#include <cstddef>

// ---------------- constants ----------------
// B=2 T=1024 H=4096 HK=8 HV=32 DK=64 DV=64 VPK=4
// GEMM1: A[2048][4096] * Wt1[5248(pad 5184)][4096]^T -> qkvz[2048][5184]
// GEMM2: on[2048][2048] * Wt2[4096][2048]^T -> out[2048][4096] (fp32)
// Both: gemm128w2 -- 128x128 tile, 2 waves x 64x128 C-slab (12 ds_read_b128
// per 32 MFMA), 3-buffer pipeline, counted vmcnt, XCD swizzle, 656/512 blocks.
// Scan: O = OR + G@S, S' = e63*S + KR - H@S  (G,H,OR,KR from precompute2)

typedef __attribute__((ext_vector_type(8))) short short8;
typedef __attribute__((ext_vector_type(4))) float f32x4;

__device__ __forceinline__ short f2bf(float f) {
  union { float f; unsigned u; } x; x.f = f;
  unsigned r = x.u + 0x7fffu + ((x.u >> 16) & 1u);
  return (short)(r >> 16);
}

__device__ __forceinline__ void gl_lds16(const short* g, short* l) {
  __builtin_amdgcn_global_load_lds(
      (const __attribute__((address_space(1))) void*)g,
      (__attribute__((address_space(3))) void*)l, 16, 0, 0);
}

// ---------------- elementwise fp32 -> bf16 ----------------
__global__ __launch_bounds__(256) void to_bf16_kernel(const float* __restrict__ x,
                                                      short* __restrict__ y) {
  int i = blockIdx.x * 256 + threadIdx.x;   // one float4 per thread
  float4 v = ((const float4*)x)[i];
  ushort4 r;
  r.x = (unsigned short)f2bf(v.x);
  r.y = (unsigned short)f2bf(v.y);
  r.z = (unsigned short)f2bf(v.z);
  r.w = (unsigned short)f2bf(v.w);
  ((ushort4*)y)[i] = r;
}

// ---------------- transpose+convert W_qkvz|W_ba -> Wt1[n][k], pad to 5248 ----------------
__global__ __launch_bounds__(256) void transpose_w1(const float* __restrict__ Wq,
                                                    const float* __restrict__ Wba,
                                                    short* __restrict__ Wt) {
  __shared__ float tile[32][33];
  int n0 = blockIdx.x * 32;  // < 5248
  int k0 = blockIdx.y * 32;  // < 4096
  int t = threadIdx.x;
  int r = t >> 5;    // 0..7
  int c = t & 31;
#pragma unroll
  for (int i = 0; i < 4; ++i) {
    int kl = r + i * 8;
    int n = n0 + c;
    float v = 0.f;
    if (n < 5120) v = Wq[(size_t)(k0 + kl) * 5120 + n];
    else if (n < 5184) v = Wba[(size_t)(k0 + kl) * 64 + (n - 5120)];
    tile[kl][c] = v;
  }
  __syncthreads();
#pragma unroll
  for (int i = 0; i < 4; ++i) {
    int nl = r + i * 8;
    int kl = c;
    Wt[(size_t)(n0 + nl) * 4096 + k0 + kl] = f2bf(tile[kl][nl]);
  }
}

// ---------------- transpose+convert W_out -> Wt2[n][k] ----------------
__global__ __launch_bounds__(256) void transpose_w2(const float* __restrict__ W,
                                                    short* __restrict__ Wt) {
  __shared__ float tile[32][33];
  int n0 = blockIdx.x * 32;  // < 4096
  int k0 = blockIdx.y * 32;  // < 2048
  int t = threadIdx.x;
  int r = t >> 5;
  int c = t & 31;
#pragma unroll
  for (int i = 0; i < 4; ++i) {
    int kl = r + i * 8;
    tile[kl][c] = W[(size_t)(k0 + kl) * 4096 + n0 + c];
  }
  __syncthreads();
#pragma unroll
  for (int i = 0; i < 4; ++i) {
    int nl = r + i * 8;
    int kl = c;
    Wt[(size_t)(n0 + nl) * 2048 + k0 + kl] = f2bf(tile[kl][nl]);
  }
}

// ---------------- 128x128 pipelined bf16 MFMA GEMM, 2 waves (3-stage) ----------
// BM=BN=128, BK=32, 128 threads = 2 waves; wave w owns C rows [w*64, w*64+64)
// x all 128 cols = 4x8 fragments -> 12 ds_read_b128 per 32 MFMA (the LDS-read
// lever) while KEEPING the 656-block grid (fill lever; 3 blocks/CU at 48 KiB).
// 3 LDS buffers; staging of kt+2 -> (kt+2)%3; vmcnt(8) steady (8 loads/tile:
// 4 rounds A of 32 rows + 4 rounds B), drain only in the 2-tile epilogue.
// LDS slot permutation (proven 0-conflict): slot p -> row rp*2+(mm>>2),
// scol (mm&3)*8, mm = (p&7)^((p>>3)&7); global source pre-permuted, LDS dest
// linear.  Grid 1-D, bijective XCD swizzle (nwg%8==0).
template <bool GUARD_N>
__global__ __launch_bounds__(128) void gemm128w2(const short* __restrict__ A,
                                                 const short* __restrict__ Bt,
                                                 float* __restrict__ C,
                                                 int N, int K, int MT) {
  __shared__ __align__(16) short As[3 * 4096];
  __shared__ __align__(16) short Bs[3 * 4096];
  const int tid = threadIdx.x;
  const int w = tid >> 6, lane = tid & 63;

  const int nwg = gridDim.x;
  const int bid = blockIdx.x;
  const int swz = (bid & 7) * (nwg >> 3) + (bid >> 3);
  const int m0 = (swz % MT) * 128;
  const int n0 = (swz / MT) * 128;

  // staging: phys slot p0 = tid (0..127) -> (row 0..31, s); rounds add 32 rows
  const int rp0 = tid >> 3, q0 = tid & 7;
  const int mm0 = q0 ^ (rp0 & 7);
  const int srow = rp0 * 2 + (mm0 >> 2);     // 0..31
  const int scol = (mm0 & 3) << 3;           // elem offset 0/8/16/24
  const short* Ag = A + (size_t)(m0 + srow) * K + scol;
  const short* Bg = Bt + (size_t)(n0 + srow) * K + scol;
  const size_t rstep = (size_t)32 * K;       // 32 rows per staging round

  // fragment read offsets: row = frag base + (lane&15), s = lane>>4
  const int fr = lane & 15;
  const int s = lane >> 4;
  int aoff[4], boff[8];
#pragma unroll
  for (int i = 0; i < 4; ++i) {
    int row = w * 64 + i * 16 + fr;          // wave's 64 M-rows
    int rp = row >> 1;
    int q = (((row & 1) << 2) | s) ^ (rp & 7);
    aoff[i] = (rp * 8 + q) * 8;
  }
#pragma unroll
  for (int j = 0; j < 8; ++j) {
    int row = j * 16 + fr;                   // all 128 N-rows
    int rp = row >> 1;
    int q = (((row & 1) << 2) | s) ^ (rp & 7);
    boff[j] = (rp * 8 + q) * 8;
  }

  f32x4 acc[4][8];
#pragma unroll
  for (int i = 0; i < 4; ++i)
#pragma unroll
    for (int j = 0; j < 8; ++j) acc[i][j] = (f32x4){0.f, 0.f, 0.f, 0.f};

  const int NKT = K >> 5;

#define STAGE_A(kt, bb)                                                  \
  { const short* g = Ag + (size_t)(kt) * 32;                             \
    gl_lds16(g,             &As[(bb) * 4096 + (w << 9)]);                \
    gl_lds16(g + rstep,     &As[(bb) * 4096 + 1024 + (w << 9)]);         \
    gl_lds16(g + 2 * rstep, &As[(bb) * 4096 + 2048 + (w << 9)]);         \
    gl_lds16(g + 3 * rstep, &As[(bb) * 4096 + 3072 + (w << 9)]); }
#define STAGE_B(kt, bb)                                                  \
  { const short* g = Bg + (size_t)(kt) * 32;                             \
    gl_lds16(g,             &Bs[(bb) * 4096 + (w << 9)]);                \
    gl_lds16(g + rstep,     &Bs[(bb) * 4096 + 1024 + (w << 9)]);         \
    gl_lds16(g + 2 * rstep, &Bs[(bb) * 4096 + 2048 + (w << 9)]);         \
    gl_lds16(g + 3 * rstep, &Bs[(bb) * 4096 + 3072 + (w << 9)]); }

  // prologue: stage kt0 -> buf0, kt1 -> buf1; wait kt0 resident (8 in flight ok)
  STAGE_A(0, 0); STAGE_B(0, 0);
  STAGE_A(1, 1); STAGE_B(1, 1);
  asm volatile("s_waitcnt vmcnt(8)" ::: "memory");
  __builtin_amdgcn_s_barrier();
  __builtin_amdgcn_sched_barrier(0);

  int bi = 0;
  for (int kt = 0; kt < NKT; ++kt) {
    int bi2 = bi - 1; if (bi2 < 0) bi2 = 2;   // (kt+2)%3
    const short* Ab = &As[bi * 4096];
    const short* Bb = &Bs[bi * 4096];
    short8 af[4], bf[4];
    // ---- phase 1: frags(m0-3, n0-3) + stage A(kt+2) ----
#pragma unroll
    for (int i = 0; i < 4; ++i) af[i] = *(const short8*)&Ab[aoff[i]];
#pragma unroll
    for (int j = 0; j < 4; ++j) bf[j] = *(const short8*)&Bb[boff[j]];
    if (kt + 2 < NKT) STAGE_A(kt + 2, bi2);
    __builtin_amdgcn_s_barrier();
    asm volatile("s_waitcnt lgkmcnt(0)" ::: "memory");
    __builtin_amdgcn_sched_barrier(0);
    __builtin_amdgcn_s_setprio(1);
#pragma unroll
    for (int i = 0; i < 4; ++i)
#pragma unroll
      for (int j = 0; j < 4; ++j)
        acc[i][j] = __builtin_amdgcn_mfma_f32_16x16x32_bf16(af[i], bf[j], acc[i][j], 0, 0, 0);
    __builtin_amdgcn_s_setprio(0);
    __builtin_amdgcn_sched_barrier(0);
    // ---- phase 2: frags(n4-7) + stage B(kt+2); counted vmcnt ----
#pragma unroll
    for (int j = 0; j < 4; ++j) bf[j] = *(const short8*)&Bb[boff[j + 4]];
    if (kt + 2 < NKT) STAGE_B(kt + 2, bi2);
    if (kt < NKT - 2) { asm volatile("s_waitcnt vmcnt(8)" ::: "memory"); }
    else              { asm volatile("s_waitcnt vmcnt(0)" ::: "memory"); }
    __builtin_amdgcn_s_barrier();
    asm volatile("s_waitcnt lgkmcnt(0)" ::: "memory");
    __builtin_amdgcn_sched_barrier(0);
    __builtin_amdgcn_s_setprio(1);
#pragma unroll
    for (int i = 0; i < 4; ++i)
#pragma unroll
      for (int j = 0; j < 4; ++j)
        acc[i][j + 4] = __builtin_amdgcn_mfma_f32_16x16x32_bf16(af[i], bf[j], acc[i][j + 4], 0, 0, 0);
    __builtin_amdgcn_s_setprio(0);
    __builtin_amdgcn_sched_barrier(0);
    __builtin_amdgcn_s_barrier();   // trailing: makes next-iter staging into bi safe
    ++bi; if (bi == 3) bi = 0;
  }
#undef STAGE_A
#undef STAGE_B

  // C/D layout: col = lane&15, row = (lane>>4)*4 + r
  const int rbase = (lane >> 4) << 2;
#pragma unroll
  for (int i = 0; i < 4; ++i) {
#pragma unroll
    for (int j = 0; j < 8; ++j) {
      int col = n0 + j * 16 + fr;
      if (GUARD_N && col >= N) continue;
      int row = m0 + w * 64 + i * 16 + rbase;
#pragma unroll
      for (int r = 0; r < 4; ++r)
        C[(size_t)(row + r) * N + col] = acc[i][j][r];
    }
  }
}

// ---------------- conv(4-tap causal) + silu + l2norm(q,k) ----------------
__global__ __launch_bounds__(256) void conv_kernel(const float* __restrict__ qkvz,
                                                   const float* __restrict__ conv_w,
                                                   float* __restrict__ mix) {
  __shared__ float sq[1024];
  __shared__ float scale[16];
  int bt = blockIdx.x;       // b*1024 + t
  int t = bt & 1023;
  int tid = threadIdx.x;
  for (int c = tid; c < 3072; c += 256) {
    int col;
    if (c < 512) {
      col = (c >> 6) * 640 + (c & 63);
    } else if (c < 1024) {
      int c2 = c - 512;
      col = (c2 >> 6) * 640 + 64 + (c2 & 63);
    } else {
      int c3 = c - 1024;
      int hv = c3 >> 6;
      col = (hv >> 2) * 640 + 128 + (hv & 3) * 64 + (c3 & 63);
    }
    float acc = 0.f;
#pragma unroll
    for (int j = 0; j < 4; ++j) {
      int tt = t - 3 + j;
      if (tt >= 0) acc += qkvz[(size_t)(bt - 3 + j) * 5184 + col] * conv_w[c * 4 + j];
    }
    float sv = acc / (1.f + __expf(-acc));  // silu
    if (c < 1024)
      sq[c] = sv;
    else
      mix[(size_t)bt * 3072 + c] = sv;
  }
  __syncthreads();
  int g = tid >> 4, l = tid & 15;
  float p = 0.f;
#pragma unroll
  for (int i = 0; i < 4; ++i) {
    float v = sq[g * 64 + l * 4 + i];
    p += v * v;
  }
  p += __shfl_xor(p, 1);
  p += __shfl_xor(p, 2);
  p += __shfl_xor(p, 4);
  p += __shfl_xor(p, 8);
  if (l == 0) scale[g] = rsqrtf(p + 1e-6f);
  __syncthreads();
  for (int c = tid; c < 1024; c += 256) {
    float s = scale[c >> 6] * ((c < 512) ? 0.125f : 1.f);  // q gets DK^-0.5
    mix[(size_t)bt * 3072 + c] = sq[c] * s;
  }
}

// ---------------- gates: g (log-decay) and beta = sigmoid(b) ----------------
__global__ __launch_bounds__(256) void gate_kernel(const float* __restrict__ qkvz,
                                                   const float* __restrict__ dt_bias,
                                                   const float* __restrict__ A_log,
                                                   float* __restrict__ gb,
                                                   float* __restrict__ beta) {
  int i = blockIdx.x * 256 + threadIdx.x;  // < 65536 = 2048*32
  int hv = i & 31;
  int bt = i >> 5;
  int hk = hv >> 2, vp = hv & 3;
  const float* row = qkvz + (size_t)bt * 5184 + 5120 + hk * 8;
  float bv = row[vp];
  float av = row[4 + vp];
  float x = av + dt_bias[hv];
  float sp = (x > 20.f) ? x : log1pf(expf(x));
  gb[i] = -expf(A_log[hv]) * sp;        // log-decay g_t (<= 0)
  beta[i] = 1.f / (1.f + expf(-bv));
}

// ---------------- chunked delta-rule precompute (stage 1, unchanged) ----------------
__global__ __launch_bounds__(256) void precompute_kernel(
    const float* __restrict__ mix, const float* __restrict__ gbuf,
    const float* __restrict__ betab, float* __restrict__ Wbuf,
    float* __restrict__ Pbuf, float* __restrict__ Rbuf, float* __restrict__ cbuf) {
  __shared__ float Kt[64][68];   // K col-major: Kt[d][t]; later K' row-major scaled
  __shared__ float Vb[64][68];   // V row-major
  __shared__ float AM[64][68];   // A; later Q col-major
  __shared__ float Mm[64][68];   // (I+A)^{-1}
  __shared__ float Tb[16][17];
  __shared__ float cs[64], bb[64];

  const int u = blockIdx.x;
  const int chunk = u & 15, hv = (u >> 4) & 31, b = u >> 9;
  const int hk = hv >> 2;
  const int t0g = b * 1024 + chunk * 64;
  const int tid = threadIdx.x;
  const int tr = tid >> 2, q4 = tid & 3;

  {
    const float* mrow = mix + (size_t)(t0g + tr) * 3072;
#pragma unroll
    for (int e = 0; e < 4; ++e) {
      int c0 = q4 * 16 + e * 4;
      float4 kv = *(const float4*)(mrow + 512 + hk * 64 + c0);
      Kt[c0 + 0][tr] = kv.x; Kt[c0 + 1][tr] = kv.y;
      Kt[c0 + 2][tr] = kv.z; Kt[c0 + 3][tr] = kv.w;
      *(float4*)&Vb[tr][c0] = *(const float4*)(mrow + 1024 + hv * 64 + c0);
    }
  }
  if (tid < 64) {
    cs[tid] = gbuf[(size_t)(t0g + tid) * 32 + hv];
    bb[tid] = betab[(size_t)(t0g + tid) * 32 + hv];
  }
  __syncthreads();
  for (int off = 1; off < 64; off <<= 1) {
    float v = 0.f;
    if (tid < 64 && tid >= off) v = cs[tid - off];
    __syncthreads();
    if (tid < 64) cs[tid] += v;
    __syncthreads();
  }
  if (tid < 64) cbuf[(size_t)u * 64 + tid] = cs[tid];

  {
    float acc[16];
#pragma unroll
    for (int i = 0; i < 16; ++i) acc[i] = 0.f;
    for (int d = 0; d < 64; ++d) {
      float kv = Kt[d][tr];
#pragma unroll
      for (int e = 0; e < 4; ++e) {
        float4 ks = *(const float4*)&Kt[d][q4 * 16 + e * 4];
        acc[e * 4 + 0] += kv * ks.x; acc[e * 4 + 1] += kv * ks.y;
        acc[e * 4 + 2] += kv * ks.z; acc[e * 4 + 3] += kv * ks.w;
      }
    }
    float bt_ = bb[tr], ct_ = cs[tr];
#pragma unroll
    for (int j = 0; j < 16; ++j) {
      int s = q4 * 16 + j;
      AM[tr][s] = (s < tr) ? bt_ * acc[j] * __expf(ct_ - cs[s]) : 0.f;
    }
  }
  __syncthreads();

  for (int i = tid; i < 64 * 68; i += 256) (&Mm[0][0])[i] = 0.f;
  __syncthreads();
  if (tid < 64) {
    int blk = tid >> 4, j = tid & 15, base = blk * 16;
    Mm[base][base + j] = (j == 0) ? 1.f : 0.f;
    for (int r = 1; r < 16; ++r) {
      float sum = 0.f;
      for (int s = 0; s < r; ++s) sum += AM[base + r][base + s] * Mm[base + s][base + j];
      Mm[base + r][base + j] = ((r == j) ? 1.f : 0.f) - sum;
    }
  }
  __syncthreads();
  for (int d = 1; d < 4; ++d) {
    for (int j = 0; j + d < 4; ++j) {
      int i = j + d;
      int r = tid >> 4, c = tid & 15;
      float tsum = 0.f;
      for (int kb = j; kb < i; ++kb)
        for (int uu = 0; uu < 16; ++uu)
          tsum += AM[i * 16 + r][kb * 16 + uu] * Mm[kb * 16 + uu][j * 16 + c];
      Tb[r][c] = tsum;
      __syncthreads();
      float msum = 0.f;
      for (int uu = 0; uu < 16; ++uu)
        msum += Mm[i * 16 + r][i * 16 + uu] * Tb[uu][c];
      __syncthreads();
      Mm[i * 16 + r][j * 16 + c] = -msum;
      __syncthreads();
    }
  }

  {
    const float* mrow = mix + (size_t)(t0g + tr) * 3072 + hk * 64;
#pragma unroll
    for (int e = 0; e < 4; ++e) {
      int c0 = q4 * 16 + e * 4;
      float4 qv = *(const float4*)(mrow + c0);
      AM[c0 + 0][tr] = qv.x; AM[c0 + 1][tr] = qv.y;
      AM[c0 + 2][tr] = qv.z; AM[c0 + 3][tr] = qv.w;
    }
  }
  __syncthreads();

  {
    float acc[16];
#pragma unroll
    for (int i = 0; i < 16; ++i) acc[i] = 0.f;
    for (int d = 0; d < 64; ++d) {
      float qv = AM[d][tr];
#pragma unroll
      for (int e = 0; e < 4; ++e) {
        float4 ks = *(const float4*)&Kt[d][q4 * 16 + e * 4];
        acc[e * 4 + 0] += qv * ks.x; acc[e * 4 + 1] += qv * ks.y;
        acc[e * 4 + 2] += qv * ks.z; acc[e * 4 + 3] += qv * ks.w;
      }
    }
    float ct_ = cs[tr];
#pragma unroll
    for (int e = 0; e < 4; ++e) {
      int s0 = q4 * 16 + e * 4;
      float4 pv;
      pv.x = (s0 + 0 <= tr) ? acc[e * 4 + 0] * __expf(ct_ - cs[s0 + 0]) : 0.f;
      pv.y = (s0 + 1 <= tr) ? acc[e * 4 + 1] * __expf(ct_ - cs[s0 + 1]) : 0.f;
      pv.z = (s0 + 2 <= tr) ? acc[e * 4 + 2] * __expf(ct_ - cs[s0 + 2]) : 0.f;
      pv.w = (s0 + 3 <= tr) ? acc[e * 4 + 3] * __expf(ct_ - cs[s0 + 3]) : 0.f;
      *(float4*)&Pbuf[(size_t)u * 4096 + tr * 64 + s0] = pv;
    }
  }
  __syncthreads();

  {
    float vals[16];
#pragma unroll
    for (int j = 0; j < 16; ++j) vals[j] = Kt[q4 * 16 + j][tr];
    float sc = bb[tr] * __expf(cs[tr]);
    __syncthreads();
#pragma unroll
    for (int j = 0; j < 16; ++j) Kt[tr][q4 * 16 + j] = vals[j] * sc;
  }
  __syncthreads();

  {
    float acc[16];
#pragma unroll
    for (int i = 0; i < 16; ++i) acc[i] = 0.f;
    for (int s = 0; s < 64; ++s) {
      float m = Mm[tr][s];
#pragma unroll
      for (int e = 0; e < 4; ++e) {
        float4 kk = *(const float4*)&Kt[s][q4 * 16 + e * 4];
        acc[e * 4 + 0] += m * kk.x; acc[e * 4 + 1] += m * kk.y;
        acc[e * 4 + 2] += m * kk.z; acc[e * 4 + 3] += m * kk.w;
      }
    }
#pragma unroll
    for (int e = 0; e < 4; ++e) {
      float4 wv = {acc[e * 4 + 0], acc[e * 4 + 1], acc[e * 4 + 2], acc[e * 4 + 3]};
      *(float4*)&Wbuf[(size_t)u * 4096 + tr * 64 + q4 * 16 + e * 4] = wv;
    }
  }
  {
    float acc[16];
#pragma unroll
    for (int i = 0; i < 16; ++i) acc[i] = 0.f;
    for (int s = 0; s < 64; ++s) {
      float m = Mm[tr][s] * bb[s];
#pragma unroll
      for (int e = 0; e < 4; ++e) {
        float4 vv = *(const float4*)&Vb[s][q4 * 16 + e * 4];
        acc[e * 4 + 0] += m * vv.x; acc[e * 4 + 1] += m * vv.y;
        acc[e * 4 + 2] += m * vv.z; acc[e * 4 + 3] += m * vv.w;
      }
    }
#pragma unroll
    for (int e = 0; e < 4; ++e) {
      float4 rv = {acc[e * 4 + 0], acc[e * 4 + 1], acc[e * 4 + 2], acc[e * 4 + 3]};
      *(float4*)&Rbuf[(size_t)u * 4096 + tr * 64 + q4 * 16 + e * 4] = rv;
    }
  }
}

// ---------------- precompute2: batched [P;Kt] @ [W|R] -> G,H,OR,KR (fp32) -------
__global__ __launch_bounds__(256) void precompute2_kernel(
    const float* __restrict__ mix, const float* __restrict__ cbuf,
    float* __restrict__ Wbuf, float* __restrict__ Pbuf, float* __restrict__ Rbuf,
    float* __restrict__ Hbuf) {
  __shared__ float At[64][132];
  __shared__ float Bsm[64][188];

  const int u = blockIdx.x;
  const int chunk = u & 15, hv = (u >> 4) & 31, b = u >> 9;
  const int hk = hv >> 2;
  const int t0g = b * 1024 + chunk * 64;
  const int tid = threadIdx.x;
  const int tr = tid >> 2, q4 = tid & 3;

  const float c63 = cbuf[(size_t)u * 64 + 63];
  const float csr = cbuf[(size_t)u * 64 + tr];
  const float sKv = __expf(c63 - csr);

  // ---- stage: P^T into At[0:64][m<64], scaled-K into At[t][64+kd] ----
  {
    const float* Pr = Pbuf + (size_t)u * 4096 + tr * 64;
#pragma unroll
    for (int e = 0; e < 4; ++e) {
      int k0 = q4 * 16 + e * 4;
      float4 p4 = *(const float4*)(Pr + k0);
      At[k0 + 0][tr] = p4.x; At[k0 + 1][tr] = p4.y;
      At[k0 + 2][tr] = p4.z; At[k0 + 3][tr] = p4.w;
    }
    const float* Kr = mix + (size_t)(t0g + tr) * 3072 + 512 + hk * 64;
#pragma unroll
    for (int e = 0; e < 4; ++e) {
      int n = q4 * 16 + e * 4;
      float4 k4 = *(const float4*)(Kr + n);
      float4 o4 = {k4.x * sKv, k4.y * sKv, k4.z * sKv, k4.w * sKv};
      *(float4*)&At[tr][64 + n] = o4;
    }
  }
  // ---- stage: B rows (W | R), swizzled ----
  {
    const float* Wr = Wbuf + (size_t)u * 4096 + tr * 64;
    const float* Rr = Rbuf + (size_t)u * 4096 + tr * 64;
#pragma unroll
    for (int e = 0; e < 4; ++e) {
      int n = q4 * 16 + e * 4;
      int cp = n + ((n >> 3) << 2);
      *(float4*)&Bsm[tr][cp] = *(const float4*)(Wr + n);
      *(float4*)&Bsm[tr][cp + 96] = *(const float4*)(Rr + n);  // col'(64+n)=col'(n)+96
    }
  }
  __syncthreads();

  // ---- compute: 8x8 register tile per thread ----
  const int m0 = (tid >> 4) << 3;   // 0..120
  const int n0 = (tid & 15) << 3;   // 0..120
  const int cb = n0 + ((n0 >> 3) << 2);
  float acc[8][8];
#pragma unroll
  for (int i = 0; i < 8; ++i)
#pragma unroll
    for (int j = 0; j < 8; ++j) acc[i][j] = 0.f;

  for (int k = 0; k < 64; ++k) {
    float4 a0 = *(const float4*)&At[k][m0];
    float4 a1 = *(const float4*)&At[k][m0 + 4];
    float4 b0 = *(const float4*)&Bsm[k][cb];
    float4 b1 = *(const float4*)&Bsm[k][cb + 4];
    float am[8] = {a0.x, a0.y, a0.z, a0.w, a1.x, a1.y, a1.z, a1.w};
    float bn[8] = {b0.x, b0.y, b0.z, b0.w, b1.x, b1.y, b1.z, b1.w};
#pragma unroll
    for (int i = 0; i < 8; ++i)
#pragma unroll
      for (int j = 0; j < 8; ++j) acc[i][j] += am[i] * bn[j];
  }

  // ---- epilogue: route quadrants (uniform per thread) ----
  if (m0 < 64) {
    if (n0 < 64) {
      // G[t][kd] = Q[t][kd]*exp(cs[t]) - PW
#pragma unroll
      for (int i = 0; i < 8; ++i) {
        int t = m0 + i;
        float ee = __expf(cbuf[(size_t)u * 64 + t]);
        const float* Qr = mix + (size_t)(t0g + t) * 3072 + hk * 64 + n0;
        float4 q0 = *(const float4*)(Qr);
        float4 q1 = *(const float4*)(Qr + 4);
        float4 g0 = {q0.x * ee - acc[i][0], q0.y * ee - acc[i][1],
                     q0.z * ee - acc[i][2], q0.w * ee - acc[i][3]};
        float4 g1 = {q1.x * ee - acc[i][4], q1.y * ee - acc[i][5],
                     q1.z * ee - acc[i][6], q1.w * ee - acc[i][7]};
        float* dst = Wbuf + (size_t)u * 4096 + t * 64 + n0;
        *(float4*)dst = g0; *(float4*)(dst + 4) = g1;
      }
    } else {
#pragma unroll
      for (int i = 0; i < 8; ++i) {
        float* dst = Rbuf + (size_t)u * 4096 + (m0 + i) * 64 + (n0 - 64);
        float4 r0 = {acc[i][0], acc[i][1], acc[i][2], acc[i][3]};
        float4 r1 = {acc[i][4], acc[i][5], acc[i][6], acc[i][7]};
        *(float4*)dst = r0; *(float4*)(dst + 4) = r1;
      }
    }
  } else {
    if (n0 < 64) {
#pragma unroll
      for (int i = 0; i < 8; ++i) {
        float* dst = Hbuf + (size_t)u * 4096 + (m0 - 64 + i) * 64 + n0;
        float4 h0 = {acc[i][0], acc[i][1], acc[i][2], acc[i][3]};
        float4 h1 = {acc[i][4], acc[i][5], acc[i][6], acc[i][7]};
        *(float4*)dst = h0; *(float4*)(dst + 4) = h1;
      }
    } else {
#pragma unroll
      for (int i = 0; i < 8; ++i) {
        float* dst = Pbuf + (size_t)u * 4096 + (m0 - 64 + i) * 64 + (n0 - 64);
        float4 k0v = {acc[i][0], acc[i][1], acc[i][2], acc[i][3]};
        float4 k1v = {acc[i][4], acc[i][5], acc[i][6], acc[i][7]};
        *(float4*)dst = k0v; *(float4*)(dst + 4) = k1v;
      }
    }
  }
}

// ---------------- chunked serial scan (v5: 512 thr, 2 cols/thread) ------------
// O = OR + G@S, S' = e63*S + KR - H@S.  Thread (tr 0..63, q8 0..7) owns cols
// {2q8, 2q8+1}: G/H row reads amortize over both cols -> 64 b128/thread/chunk,
// 8 waves -> 512 wave-instructions/chunk (-33% vs v4).  2 barriers/chunk.
__global__ __launch_bounds__(512) void chunk_scan_kernel(
    const float* __restrict__ Gbuf, const float* __restrict__ Hbuf,
    const float* __restrict__ ORbuf, const float* __restrict__ KRbuf,
    const float* __restrict__ cbuf, float* __restrict__ o) {
  __shared__ float Gs[64][68], Hs[64][68];
  __shared__ float St[16][68];

  const int bid = blockIdx.x;
  const int vs = bid & 3, hv = (bid >> 2) & 31, b = bid >> 7;
  const int bh = b * 32 + hv;
  const int ubase = bh * 16;
  const int tid = threadIdx.x;
  const int tr = tid >> 3, q8 = tid & 7;
  const int c0 = q8 * 2, c1 = q8 * 2 + 1;

  // zero S^T state (16*68 = 1088 floats)
  for (int i = tid; i < 16 * 68; i += 512) (&St[0][0])[i] = 0.f;

  float4 GN[2], HN[2];
  float2 ORn, KRn;
  float e63n = 0.f;

#define ISSUE(ch)                                                               \
  {                                                                             \
    size_t uu = (size_t)(ubase + (ch));                                         \
    _Pragma("unroll") for (int i = 0; i < 2; ++i) {                             \
      GN[i] = ((const float4*)(Gbuf + uu * 4096))[tid + 512 * i];               \
      HN[i] = ((const float4*)(Hbuf + uu * 4096))[tid + 512 * i];               \
    }                                                                           \
    ORn = *(const float2*)(ORbuf + uu * 4096 + tr * 64 + vs * 16 + q8 * 2);     \
    KRn = *(const float2*)(KRbuf + uu * 4096 + tr * 64 + vs * 16 + q8 * 2);     \
    e63n = cbuf[uu * 64 + 63];                                                  \
  }

#define COMMIT()                                                                \
  {                                                                             \
    _Pragma("unroll") for (int i = 0; i < 2; ++i) {                             \
      int flat = (tid + 512 * i) * 4;                                           \
      int rr = flat >> 6, cc = flat & 63;                                       \
      *(float4*)&Gs[rr][cc] = GN[i];                                            \
      *(float4*)&Hs[rr][cc] = HN[i];                                            \
    }                                                                           \
  }

  ISSUE(0);
  COMMIT();
  float2 ORv = ORn, KRv = KRn;
  float e63 = __expf(e63n);
  __syncthreads();

  for (int c = 0; c < 16; ++c) {
    if (c < 15) ISSUE(c + 1);
    float op0 = ORv.x, op1 = ORv.y, sn0 = KRv.x, sn1 = KRv.y;
    float sold0 = St[c0][tr], sold1 = St[c1][tr];
#pragma unroll
    for (int i = 0; i < 16; ++i) {
      float4 g4 = *(const float4*)&Gs[tr][i * 4];
      float4 h4 = *(const float4*)&Hs[tr][i * 4];
      float4 sa = *(const float4*)&St[c0][i * 4];
      float4 sb = *(const float4*)&St[c1][i * 4];
      op0 += g4.x * sa.x + g4.y * sa.y + g4.z * sa.z + g4.w * sa.w;
      op1 += g4.x * sb.x + g4.y * sb.y + g4.z * sb.z + g4.w * sb.w;
      sn0 -= h4.x * sa.x + h4.y * sa.y + h4.z * sa.z + h4.w * sa.w;
      sn1 -= h4.x * sb.x + h4.y * sb.y + h4.z * sb.z + h4.w * sb.w;
    }
    *(float2*)&o[((size_t)(bh * 4 + vs) * 1024 + c * 64 + tr) * 16 + q8 * 2] =
        (float2){op0, op1};
    float snew0 = sold0 * e63 + sn0;
    float snew1 = sold1 * e63 + sn1;
    __syncthreads();              // all G/H/S reads of this chunk done
    St[c0][tr] = snew0;
    St[c1][tr] = snew1;
    if (c < 15) {
      COMMIT();
      ORv = ORn; KRv = KRn; e63 = __expf(e63n);
    }
    __syncthreads();              // St + next G/H visible
  }
#undef ISSUE
#undef COMMIT
}

// ---------------- rmsnorm * norm_w * silu(z), -> bf16 ----------------
__global__ __launch_bounds__(256) void rms_gate_kernel(const float* __restrict__ o,
                                                       const float* __restrict__ qkvz,
                                                       const float* __restrict__ norm_w,
                                                       short* __restrict__ on) {
  int bid = blockIdx.x;            // (bh)*256 + tgroup
  int bh = bid >> 8;               // b*32+hv
  int tg = bid & 255;
  int b = bh >> 5, hv = bh & 31;
  int t = tg * 4 + (threadIdx.x >> 6);
  int d = threadIdx.x & 63;
  int bt = b * 1024 + t;
  int hk = hv >> 2, vp = hv & 3;
  float x = o[((size_t)(bh * 4 + (d >> 4)) * 1024 + t) * 16 + (d & 15)];
  float ss = x * x;
  ss += __shfl_xor(ss, 1);
  ss += __shfl_xor(ss, 2);
  ss += __shfl_xor(ss, 4);
  ss += __shfl_xor(ss, 8);
  ss += __shfl_xor(ss, 16);
  ss += __shfl_xor(ss, 32);
  float sc = rsqrtf(ss * (1.f / 64.f) + 1e-5f);
  float z = qkvz[(size_t)bt * 5184 + hk * 640 + 384 + vp * 64 + d];
  float val = x * sc * norm_w[d] * (z / (1.f + __expf(-z)));
  on[((size_t)bt * 32 + hv) * 64 + d] = f2bf(val);
}

// ---------------- launch ----------------
extern "C" void kernel_launch(void* const* d_in, const int* in_sizes, int n_in,
                              void* d_out, int out_size, void* d_ws, size_t ws_size,
                              hipStream_t stream) {
  const float* hidden = (const float*)d_in[0];
  const float* W_qkvz = (const float*)d_in[1];
  const float* W_ba = (const float*)d_in[2];
  const float* conv_w = (const float*)d_in[3];
  const float* dt_bias = (const float*)d_in[4];
  const float* A_log = (const float*)d_in[5];
  const float* norm_w = (const float*)d_in[6];
  const float* W_out = (const float*)d_in[7];
  float* out = (float*)d_out;

  char* ws = (char*)d_ws;
  short* A_bf = (short*)(ws + 0);                // 16,777,216 (dead after GEMM1)
  float* Hbuf = (float*)(ws + 0);                //   reused: H [1024][64][64]
  short* Wt1 = (short*)(ws + 16777216);          // 42,991,616  [5248][4096] (pad)
  short* Wt2 = (short*)(ws + 59768832);          // 16,777,216  [4096][2048]
  float* qkvz = (float*)(ws + 76546048);         // 42,467,328  [2048][5184]
  float* mix = (float*)(ws + 119013376);         // 25,165,824  [2048][3072]
  float* gbuf = (float*)(ws + 144179200);        //    262,144  [2048][32]
  float* beta = (float*)(ws + 144441344);        //    262,144
  float* o = (float*)(ws + 144703488);           // 16,777,216  [256][1024][16]
  short* on = (short*)(ws + 161480704);          //  8,388,608  [2048][2048]
  float* Wbuf = (float*)(ws + 169869312);        // 16,777,216  W -> G (in place)
  float* Pbuf = (float*)(ws + 186646528);        // 16,777,216  P -> KR (in place)
  float* Rbuf = (float*)(ws + 203423744);        // 16,777,216  R -> OR (in place)
  float* cbuf = (float*)(ws + 220200960);        //    262,144  [1024][64]

  to_bf16_kernel<<<8192, 256, 0, stream>>>(hidden, A_bf);
  transpose_w1<<<dim3(164, 128), 256, 0, stream>>>(W_qkvz, W_ba, Wt1);
  transpose_w2<<<dim3(128, 64), 256, 0, stream>>>(W_out, Wt2);
  // GEMM1: 16x41 = 656 blocks (2.56/CU at 3/CU cap; 656%8==0 bijective XCD swz);
  // staging rows of last n-tile reach 5247 < Wt1's 5248-row pad.
  gemm128w2<true><<<656, 128, 0, stream>>>(A_bf, Wt1, qkvz, 5184, 4096, 16);
  conv_kernel<<<2048, 256, 0, stream>>>(qkvz, conv_w, mix);
  gate_kernel<<<256, 256, 0, stream>>>(qkvz, dt_bias, A_log, gbuf, beta);
  precompute_kernel<<<1024, 256, 0, stream>>>(mix, gbuf, beta, Wbuf, Pbuf, Rbuf, cbuf);
  precompute2_kernel<<<1024, 256, 0, stream>>>(mix, cbuf, Wbuf, Pbuf, Rbuf, Hbuf);
  chunk_scan_kernel<<<256, 512, 0, stream>>>(Wbuf, Hbuf, Rbuf, Pbuf, cbuf, o);
  rms_gate_kernel<<<16384, 256, 0, stream>>>(o, qkvz, norm_w, on);
  // GEMM2: 16x32 = 512 blocks, all co-resident at 3/CU.
  gemm128w2<false><<<512, 128, 0, stream>>>(on, Wt2, out, 4096, 2048, 16);
}

// Round 9
// 536.014 us; speedup vs baseline: 1.0389x; 1.0389x over previous
//
#include <hip/hip_runtime.h>
#include <hip/hip_bf16.h>
#include <cstdint>
#include <cstddef>

// ---------------- constants ----------------
// B=2 T=1024 H=4096 HK=8 HV=32 DK=64 DV=64 VPK=4
// GEMM1: A[2048][4096] * Wt1[5248(pad 5184)][4096]^T -> qkvz[2048][5184]
// GEMM2: on[2048][2048] * Wt2[4096][2048]^T -> out[2048][4096] (fp32)
// Both: gemm128p (r6 config: 4 waves, 3-buffer, counted vmcnt, XCD swizzle)
// Scan: O = OR + G@S, S' = e63*S + KR - H@S  (G,H,OR,KR from precompute2)

typedef __attribute__((ext_vector_type(8))) short short8;
typedef __attribute__((ext_vector_type(4))) float f32x4;

__device__ __forceinline__ short f2bf(float f) {
  union { float f; unsigned u; } x; x.f = f;
  unsigned r = x.u + 0x7fffu + ((x.u >> 16) & 1u);
  return (short)(r >> 16);
}

__device__ __forceinline__ void gl_lds16(const short* g, short* l) {
  __builtin_amdgcn_global_load_lds(
      (const __attribute__((address_space(1))) void*)g,
      (__attribute__((address_space(3))) void*)l, 16, 0, 0);
}

// ---------------- elementwise fp32 -> bf16 ----------------
__global__ __launch_bounds__(256) void to_bf16_kernel(const float* __restrict__ x,
                                                      short* __restrict__ y) {
  int i = blockIdx.x * 256 + threadIdx.x;   // one float4 per thread
  float4 v = ((const float4*)x)[i];
  ushort4 r;
  r.x = (unsigned short)f2bf(v.x);
  r.y = (unsigned short)f2bf(v.y);
  r.z = (unsigned short)f2bf(v.z);
  r.w = (unsigned short)f2bf(v.w);
  ((ushort4*)y)[i] = r;
}

// ---------------- transpose+convert W_qkvz|W_ba -> Wt1[n][k], pad to 5248 ----------------
__global__ __launch_bounds__(256) void transpose_w1(const float* __restrict__ Wq,
                                                    const float* __restrict__ Wba,
                                                    short* __restrict__ Wt) {
  __shared__ float tile[32][33];
  int n0 = blockIdx.x * 32;  // < 5248
  int k0 = blockIdx.y * 32;  // < 4096
  int t = threadIdx.x;
  int r = t >> 5;    // 0..7
  int c = t & 31;
#pragma unroll
  for (int i = 0; i < 4; ++i) {
    int kl = r + i * 8;
    int n = n0 + c;
    float v = 0.f;
    if (n < 5120) v = Wq[(size_t)(k0 + kl) * 5120 + n];
    else if (n < 5184) v = Wba[(size_t)(k0 + kl) * 64 + (n - 5120)];
    tile[kl][c] = v;
  }
  __syncthreads();
#pragma unroll
  for (int i = 0; i < 4; ++i) {
    int nl = r + i * 8;
    int kl = c;
    Wt[(size_t)(n0 + nl) * 4096 + k0 + kl] = f2bf(tile[kl][nl]);
  }
}

// ---------------- transpose+convert W_out -> Wt2[n][k] ----------------
__global__ __launch_bounds__(256) void transpose_w2(const float* __restrict__ W,
                                                    short* __restrict__ Wt) {
  __shared__ float tile[32][33];
  int n0 = blockIdx.x * 32;  // < 4096
  int k0 = blockIdx.y * 32;  // < 2048
  int t = threadIdx.x;
  int r = t >> 5;
  int c = t & 31;
#pragma unroll
  for (int i = 0; i < 4; ++i) {
    int kl = r + i * 8;
    tile[kl][c] = W[(size_t)(k0 + kl) * 4096 + n0 + c];
  }
  __syncthreads();
#pragma unroll
  for (int i = 0; i < 4; ++i) {
    int nl = r + i * 8;
    int kl = c;
    Wt[(size_t)(n0 + nl) * 2048 + k0 + kl] = f2bf(tile[kl][nl]);
  }
}

// ---------------- 128x128 pipelined bf16 MFMA GEMM (3-stage, counted vmcnt) ----
// Round-6 verified config: 4 waves (2Mx2N), 48 KiB LDS -> 3 blocks/CU,
// counted vmcnt(4), 0 bank conflicts, bijective XCD swizzle.  Best measured
// of the family (111 us GEMM1); r7 (big tile, 2/CU) and r8 (2-wave) both
// regressed -> this is the empirical optimum of the 128-tile structure.
template <bool GUARD_N>
__global__ __launch_bounds__(256) void gemm128p(const short* __restrict__ A,
                                                const short* __restrict__ Bt,
                                                float* __restrict__ C,
                                                int N, int K, int MT) {
  __shared__ __align__(16) short As[3 * 4096];
  __shared__ __align__(16) short Bs[3 * 4096];
  const int tid = threadIdx.x;
  const int w = tid >> 6, lane = tid & 63;
  const int wm = w >> 1, wn = w & 1;

  const int nwg = gridDim.x;
  const int bid = blockIdx.x;
  const int swz = (bid & 7) * (nwg >> 3) + (bid >> 3);
  const int m0 = (swz % MT) * 128;
  const int n0 = (swz / MT) * 128;

  const int p0 = w * 64 + lane;
  const int rp0 = p0 >> 3, q0 = p0 & 7;
  const int mm0 = q0 ^ (rp0 & 7);
  const int srow = rp0 * 2 + (mm0 >> 2);     // 0..63 (round1 = +64)
  const int scol = (mm0 & 3) << 3;           // elem offset 0/8/16/24
  const short* Ag = A + (size_t)(m0 + srow) * K + scol;
  const short* Bg = Bt + (size_t)(n0 + srow) * K + scol;
  const size_t rstep = (size_t)64 * K;

  const int fr = lane & 15;
  const int s = lane >> 4;
  int aoff[4], boff[4];
#pragma unroll
  for (int i = 0; i < 4; ++i) {
    int row = wm * 64 + i * 16 + fr;
    int rp = row >> 1;
    int q = (((row & 1) << 2) | s) ^ (rp & 7);
    aoff[i] = (rp * 8 + q) * 8;
  }
#pragma unroll
  for (int j = 0; j < 4; ++j) {
    int row = wn * 64 + j * 16 + fr;
    int rp = row >> 1;
    int q = (((row & 1) << 2) | s) ^ (rp & 7);
    boff[j] = (rp * 8 + q) * 8;
  }

  f32x4 acc[4][4];
#pragma unroll
  for (int i = 0; i < 4; ++i)
#pragma unroll
    for (int j = 0; j < 4; ++j) acc[i][j] = (f32x4){0.f, 0.f, 0.f, 0.f};

  const int NKT = K >> 5;

#define STAGE_A(kt, bb)                                                \
  { const short* g = Ag + (size_t)(kt) * 32;                           \
    gl_lds16(g,         &As[(bb) * 4096 + w * 512]);                   \
    gl_lds16(g + rstep, &As[(bb) * 4096 + 2048 + w * 512]); }
#define STAGE_B(kt, bb)                                                \
  { const short* g = Bg + (size_t)(kt) * 32;                           \
    gl_lds16(g,         &Bs[(bb) * 4096 + w * 512]);                   \
    gl_lds16(g + rstep, &Bs[(bb) * 4096 + 2048 + w * 512]); }

  STAGE_A(0, 0); STAGE_B(0, 0);
  STAGE_A(1, 1); STAGE_B(1, 1);
  asm volatile("s_waitcnt vmcnt(4)" ::: "memory");
  __builtin_amdgcn_s_barrier();
  __builtin_amdgcn_sched_barrier(0);

  int bi = 0;
  for (int kt = 0; kt < NKT; ++kt) {
    int bi2 = bi - 1; if (bi2 < 0) bi2 = 2;   // (kt+2)%3
    const short* Ab = &As[bi * 4096];
    const short* Bb = &Bs[bi * 4096];
    short8 af[2], bf[4];
#pragma unroll
    for (int i = 0; i < 2; ++i) af[i] = *(const short8*)&Ab[aoff[i]];
#pragma unroll
    for (int j = 0; j < 4; ++j) bf[j] = *(const short8*)&Bb[boff[j]];
    if (kt + 2 < NKT) STAGE_A(kt + 2, bi2);
    __builtin_amdgcn_s_barrier();
    asm volatile("s_waitcnt lgkmcnt(0)" ::: "memory");
    __builtin_amdgcn_sched_barrier(0);
    __builtin_amdgcn_s_setprio(1);
#pragma unroll
    for (int i = 0; i < 2; ++i)
#pragma unroll
      for (int j = 0; j < 4; ++j)
        acc[i][j] = __builtin_amdgcn_mfma_f32_16x16x32_bf16(af[i], bf[j], acc[i][j], 0, 0, 0);
    __builtin_amdgcn_s_setprio(0);
    __builtin_amdgcn_sched_barrier(0);
#pragma unroll
    for (int i = 0; i < 2; ++i) af[i] = *(const short8*)&Ab[aoff[i + 2]];
    if (kt + 2 < NKT) STAGE_B(kt + 2, bi2);
    if (kt < NKT - 2) { asm volatile("s_waitcnt vmcnt(4)" ::: "memory"); }
    else              { asm volatile("s_waitcnt vmcnt(0)" ::: "memory"); }
    __builtin_amdgcn_s_barrier();
    asm volatile("s_waitcnt lgkmcnt(0)" ::: "memory");
    __builtin_amdgcn_sched_barrier(0);
    __builtin_amdgcn_s_setprio(1);
#pragma unroll
    for (int i = 0; i < 2; ++i)
#pragma unroll
      for (int j = 0; j < 4; ++j)
        acc[i + 2][j] = __builtin_amdgcn_mfma_f32_16x16x32_bf16(af[i], bf[j], acc[i + 2][j], 0, 0, 0);
    __builtin_amdgcn_s_setprio(0);
    __builtin_amdgcn_sched_barrier(0);
    __builtin_amdgcn_s_barrier();
    ++bi; if (bi == 3) bi = 0;
  }
#undef STAGE_A
#undef STAGE_B

  const int rbase = (lane >> 4) << 2;
#pragma unroll
  for (int i = 0; i < 4; ++i) {
#pragma unroll
    for (int j = 0; j < 4; ++j) {
      int col = n0 + wn * 64 + j * 16 + fr;
      if (GUARD_N && col >= N) continue;
      int row = m0 + wm * 64 + i * 16 + rbase;
#pragma unroll
      for (int r = 0; r < 4; ++r)
        C[(size_t)(row + r) * N + col] = acc[i][j][r];
    }
  }
}

// ---------------- conv(4-tap causal) + silu + l2norm(q,k) + fused gates ---------
__global__ __launch_bounds__(256) void conv_kernel(const float* __restrict__ qkvz,
                                                   const float* __restrict__ conv_w,
                                                   const float* __restrict__ dt_bias,
                                                   const float* __restrict__ A_log,
                                                   float* __restrict__ mix,
                                                   float* __restrict__ gb,
                                                   float* __restrict__ beta) {
  __shared__ float sq[1024];
  __shared__ float scale[16];
  int bt = blockIdx.x;       // b*1024 + t
  int t = bt & 1023;
  int tid = threadIdx.x;
  for (int c = tid; c < 3072; c += 256) {
    int col;
    if (c < 512) {
      col = (c >> 6) * 640 + (c & 63);
    } else if (c < 1024) {
      int c2 = c - 512;
      col = (c2 >> 6) * 640 + 64 + (c2 & 63);
    } else {
      int c3 = c - 1024;
      int hv = c3 >> 6;
      col = (hv >> 2) * 640 + 128 + (hv & 3) * 64 + (c3 & 63);
    }
    float acc = 0.f;
#pragma unroll
    for (int j = 0; j < 4; ++j) {
      int tt = t - 3 + j;
      if (tt >= 0) acc += qkvz[(size_t)(bt - 3 + j) * 5184 + col] * conv_w[c * 4 + j];
    }
    float sv = acc / (1.f + __expf(-acc));  // silu
    if (c < 1024)
      sq[c] = sv;
    else
      mix[(size_t)bt * 3072 + c] = sv;
  }
  // fused gate computation (was gate_kernel): one thread per hv
  if (tid < 32) {
    int hv2 = tid;
    int hk2 = hv2 >> 2, vp = hv2 & 3;
    const float* row = qkvz + (size_t)bt * 5184 + 5120 + hk2 * 8;
    float bv = row[vp];
    float av = row[4 + vp];
    float x = av + dt_bias[hv2];
    float sp = (x > 20.f) ? x : log1pf(expf(x));
    gb[(size_t)bt * 32 + hv2] = -expf(A_log[hv2]) * sp;   // log-decay g_t (<= 0)
    beta[(size_t)bt * 32 + hv2] = 1.f / (1.f + expf(-bv));
  }
  __syncthreads();
  int g = tid >> 4, l = tid & 15;
  float p = 0.f;
#pragma unroll
  for (int i = 0; i < 4; ++i) {
    float v = sq[g * 64 + l * 4 + i];
    p += v * v;
  }
  p += __shfl_xor(p, 1);
  p += __shfl_xor(p, 2);
  p += __shfl_xor(p, 4);
  p += __shfl_xor(p, 8);
  if (l == 0) scale[g] = rsqrtf(p + 1e-6f);
  __syncthreads();
  for (int c = tid; c < 1024; c += 256) {
    float s = scale[c >> 6] * ((c < 512) ? 0.125f : 1.f);  // q gets DK^-0.5
    mix[(size_t)bt * 3072 + c] = sq[c] * s;
  }
}

// ---------------- chunked delta-rule precompute (stage 1, 4x4-tiled matmuls) ----
// Rewrite of the four 64x64x64 fp32 matmuls from 1x16-output threads (5 LDS
// reads / 16 FMA) to 4x4-output register tiles (2 LDS reads / 16 FMA) and a
// fused W+R loop sharing the Mm reads: LDS wave-instructions per wave drop
// ~1280 -> ~460.  Bank check: Kt/Vb float4 col reads = 16 distinct stride-16B
// addrs -> 2-way conflict (free, m136); Mm row reads 4-addr broadcast.
// Inversion/prefix/staging and all outputs unchanged.
__global__ __launch_bounds__(256) void precompute_kernel(
    const float* __restrict__ mix, const float* __restrict__ gbuf,
    const float* __restrict__ betab, float* __restrict__ Wbuf,
    float* __restrict__ Pbuf, float* __restrict__ Rbuf, float* __restrict__ cbuf) {
  __shared__ float Kt[64][68];   // K col-major: Kt[d][t]; later K' row-major scaled
  __shared__ float Vb[64][68];   // V row-major
  __shared__ float AM[64][68];   // A; later Q col-major
  __shared__ float Mm[64][68];   // (I+A)^{-1}
  __shared__ float Tb[16][17];
  __shared__ float cs[64], bb[64];

  const int u = blockIdx.x;
  const int chunk = u & 15, hv = (u >> 4) & 31, b = u >> 9;
  const int hk = hv >> 2;
  const int t0g = b * 1024 + chunk * 64;
  const int tid = threadIdx.x;
  const int tr = tid >> 2, q4 = tid & 3;
  const int r4 = tid >> 4, c4 = tid & 15;   // 4x4 tile: rows r4*4+i, cols c4*4+j

  {
    const float* mrow = mix + (size_t)(t0g + tr) * 3072;
#pragma unroll
    for (int e = 0; e < 4; ++e) {
      int c0 = q4 * 16 + e * 4;
      float4 kv = *(const float4*)(mrow + 512 + hk * 64 + c0);
      Kt[c0 + 0][tr] = kv.x; Kt[c0 + 1][tr] = kv.y;
      Kt[c0 + 2][tr] = kv.z; Kt[c0 + 3][tr] = kv.w;
      *(float4*)&Vb[tr][c0] = *(const float4*)(mrow + 1024 + hv * 64 + c0);
    }
  }
  if (tid < 64) {
    cs[tid] = gbuf[(size_t)(t0g + tid) * 32 + hv];
    bb[tid] = betab[(size_t)(t0g + tid) * 32 + hv];
  }
  __syncthreads();
  for (int off = 1; off < 64; off <<= 1) {
    float v = 0.f;
    if (tid < 64 && tid >= off) v = cs[tid - off];
    __syncthreads();
    if (tid < 64) cs[tid] += v;
    __syncthreads();
  }
  if (tid < 64) cbuf[(size_t)u * 64 + tid] = cs[tid];

  // ---- A = tril(K K^T, -1) .* bb_r .* exp(cs_r - cs_s), 4x4 tile/thread ----
  {
    float acc[4][4];
#pragma unroll
    for (int i = 0; i < 4; ++i)
#pragma unroll
      for (int j = 0; j < 4; ++j) acc[i][j] = 0.f;
    for (int d = 0; d < 64; ++d) {
      float4 a4 = *(const float4*)&Kt[d][r4 * 4];
      float4 b4 = *(const float4*)&Kt[d][c4 * 4];
      float av[4] = {a4.x, a4.y, a4.z, a4.w};
      float bv[4] = {b4.x, b4.y, b4.z, b4.w};
#pragma unroll
      for (int i = 0; i < 4; ++i)
#pragma unroll
        for (int j = 0; j < 4; ++j) acc[i][j] += av[i] * bv[j];
    }
    float4 cc = *(const float4*)&cs[c4 * 4];
    float ccv[4] = {cc.x, cc.y, cc.z, cc.w};
#pragma unroll
    for (int i = 0; i < 4; ++i) {
      int row = r4 * 4 + i;
      float bt_ = bb[row], ct_ = cs[row];
      float ov[4];
#pragma unroll
      for (int j = 0; j < 4; ++j) {
        int sc = c4 * 4 + j;
        ov[j] = (sc < row) ? bt_ * acc[i][j] * __expf(ct_ - ccv[j]) : 0.f;
      }
      float4 o4 = {ov[0], ov[1], ov[2], ov[3]};
      *(float4*)&AM[row][c4 * 4] = o4;
    }
  }
  __syncthreads();

  for (int i = tid; i < 64 * 68; i += 256) (&Mm[0][0])[i] = 0.f;
  __syncthreads();
  if (tid < 64) {
    int blk = tid >> 4, j = tid & 15, base = blk * 16;
    Mm[base][base + j] = (j == 0) ? 1.f : 0.f;
    for (int r = 1; r < 16; ++r) {
      float sum = 0.f;
      for (int s = 0; s < r; ++s) sum += AM[base + r][base + s] * Mm[base + s][base + j];
      Mm[base + r][base + j] = ((r == j) ? 1.f : 0.f) - sum;
    }
  }
  __syncthreads();
  for (int d = 1; d < 4; ++d) {
    for (int j = 0; j + d < 4; ++j) {
      int i = j + d;
      int r = tid >> 4, c = tid & 15;
      float tsum = 0.f;
      for (int kb = j; kb < i; ++kb)
        for (int uu = 0; uu < 16; ++uu)
          tsum += AM[i * 16 + r][kb * 16 + uu] * Mm[kb * 16 + uu][j * 16 + c];
      Tb[r][c] = tsum;
      __syncthreads();
      float msum = 0.f;
      for (int uu = 0; uu < 16; ++uu)
        msum += Mm[i * 16 + r][i * 16 + uu] * Tb[uu][c];
      __syncthreads();
      Mm[i * 16 + r][j * 16 + c] = -msum;
      __syncthreads();
    }
  }

  {
    const float* mrow = mix + (size_t)(t0g + tr) * 3072 + hk * 64;
#pragma unroll
    for (int e = 0; e < 4; ++e) {
      int c0 = q4 * 16 + e * 4;
      float4 qv = *(const float4*)(mrow + c0);
      AM[c0 + 0][tr] = qv.x; AM[c0 + 1][tr] = qv.y;
      AM[c0 + 2][tr] = qv.z; AM[c0 + 3][tr] = qv.w;
    }
  }
  __syncthreads();

  // ---- P = tril(Q K^T, 0) .* exp(cs_t - cs_s), 4x4 tile/thread ----
  {
    float acc[4][4];
#pragma unroll
    for (int i = 0; i < 4; ++i)
#pragma unroll
      for (int j = 0; j < 4; ++j) acc[i][j] = 0.f;
    for (int d = 0; d < 64; ++d) {
      float4 a4 = *(const float4*)&AM[d][r4 * 4];   // Q col-major
      float4 b4 = *(const float4*)&Kt[d][c4 * 4];
      float av[4] = {a4.x, a4.y, a4.z, a4.w};
      float bv[4] = {b4.x, b4.y, b4.z, b4.w};
#pragma unroll
      for (int i = 0; i < 4; ++i)
#pragma unroll
        for (int j = 0; j < 4; ++j) acc[i][j] += av[i] * bv[j];
    }
    float4 cc = *(const float4*)&cs[c4 * 4];
    float ccv[4] = {cc.x, cc.y, cc.z, cc.w};
#pragma unroll
    for (int i = 0; i < 4; ++i) {
      int row = r4 * 4 + i;
      float ct_ = cs[row];
      float pv[4];
#pragma unroll
      for (int j = 0; j < 4; ++j) {
        int sc = c4 * 4 + j;
        pv[j] = (sc <= row) ? acc[i][j] * __expf(ct_ - ccv[j]) : 0.f;
      }
      float4 p4 = {pv[0], pv[1], pv[2], pv[3]};
      *(float4*)&Pbuf[(size_t)u * 4096 + row * 64 + c4 * 4] = p4;
    }
  }
  __syncthreads();

  {
    float vals[16];
#pragma unroll
    for (int j = 0; j < 16; ++j) vals[j] = Kt[q4 * 16 + j][tr];
    float sc = bb[tr] * __expf(cs[tr]);
    __syncthreads();
#pragma unroll
    for (int j = 0; j < 16; ++j) Kt[tr][q4 * 16 + j] = vals[j] * sc;
  }
  __syncthreads();

  // ---- fused W = Mm @ K', R = Mm @ diag(bb) @ V, 4x4 tiles, s unrolled x4 ----
  {
    float aw[4][4], ar[4][4];
#pragma unroll
    for (int i = 0; i < 4; ++i)
#pragma unroll
      for (int j = 0; j < 4; ++j) { aw[i][j] = 0.f; ar[i][j] = 0.f; }
    for (int s0 = 0; s0 < 64; s0 += 4) {
      float4 am[4];
#pragma unroll
      for (int i = 0; i < 4; ++i) am[i] = *(const float4*)&Mm[r4 * 4 + i][s0];
      float4 bq = *(const float4*)&bb[s0];
      float bbv[4] = {bq.x, bq.y, bq.z, bq.w};
      float kv[4][4], vv[4][4];
#pragma unroll
      for (int uu = 0; uu < 4; ++uu) {
        float4 k4 = *(const float4*)&Kt[s0 + uu][c4 * 4];
        float4 v4 = *(const float4*)&Vb[s0 + uu][c4 * 4];
        kv[uu][0] = k4.x; kv[uu][1] = k4.y; kv[uu][2] = k4.z; kv[uu][3] = k4.w;
        vv[uu][0] = v4.x; vv[uu][1] = v4.y; vv[uu][2] = v4.z; vv[uu][3] = v4.w;
      }
#pragma unroll
      for (int i = 0; i < 4; ++i) {
        float amv[4] = {am[i].x, am[i].y, am[i].z, am[i].w};
#pragma unroll
        for (int uu = 0; uu < 4; ++uu) {
          float mw = amv[uu];
          float mr = mw * bbv[uu];
#pragma unroll
          for (int j = 0; j < 4; ++j) {
            aw[i][j] += mw * kv[uu][j];
            ar[i][j] += mr * vv[uu][j];
          }
        }
      }
    }
#pragma unroll
    for (int i = 0; i < 4; ++i) {
      int row = r4 * 4 + i;
      float4 w4 = {aw[i][0], aw[i][1], aw[i][2], aw[i][3]};
      float4 rr = {ar[i][0], ar[i][1], ar[i][2], ar[i][3]};
      *(float4*)&Wbuf[(size_t)u * 4096 + row * 64 + c4 * 4] = w4;
      *(float4*)&Rbuf[(size_t)u * 4096 + row * 64 + c4 * 4] = rr;
    }
  }
}

// ---------------- precompute2: batched [P;Kt] @ [W|R] -> G,H,OR,KR (fp32) -------
__global__ __launch_bounds__(256) void precompute2_kernel(
    const float* __restrict__ mix, const float* __restrict__ cbuf,
    float* __restrict__ Wbuf, float* __restrict__ Pbuf, float* __restrict__ Rbuf,
    float* __restrict__ Hbuf) {
  __shared__ float At[64][132];
  __shared__ float Bsm[64][188];

  const int u = blockIdx.x;
  const int chunk = u & 15, hv = (u >> 4) & 31, b = u >> 9;
  const int hk = hv >> 2;
  const int t0g = b * 1024 + chunk * 64;
  const int tid = threadIdx.x;
  const int tr = tid >> 2, q4 = tid & 3;

  const float c63 = cbuf[(size_t)u * 64 + 63];
  const float csr = cbuf[(size_t)u * 64 + tr];
  const float sKv = __expf(c63 - csr);

  // ---- stage: P^T into At[0:64][m<64], scaled-K into At[t][64+kd] ----
  {
    const float* Pr = Pbuf + (size_t)u * 4096 + tr * 64;
#pragma unroll
    for (int e = 0; e < 4; ++e) {
      int k0 = q4 * 16 + e * 4;
      float4 p4 = *(const float4*)(Pr + k0);
      At[k0 + 0][tr] = p4.x; At[k0 + 1][tr] = p4.y;
      At[k0 + 2][tr] = p4.z; At[k0 + 3][tr] = p4.w;
    }
    const float* Kr = mix + (size_t)(t0g + tr) * 3072 + 512 + hk * 64;
#pragma unroll
    for (int e = 0; e < 4; ++e) {
      int n = q4 * 16 + e * 4;
      float4 k4 = *(const float4*)(Kr + n);
      float4 o4 = {k4.x * sKv, k4.y * sKv, k4.z * sKv, k4.w * sKv};
      *(float4*)&At[tr][64 + n] = o4;
    }
  }
  // ---- stage: B rows (W | R), swizzled ----
  {
    const float* Wr = Wbuf + (size_t)u * 4096 + tr * 64;
    const float* Rr = Rbuf + (size_t)u * 4096 + tr * 64;
#pragma unroll
    for (int e = 0; e < 4; ++e) {
      int n = q4 * 16 + e * 4;
      int cp = n + ((n >> 3) << 2);
      *(float4*)&Bsm[tr][cp] = *(const float4*)(Wr + n);
      *(float4*)&Bsm[tr][cp + 96] = *(const float4*)(Rr + n);  // col'(64+n)=col'(n)+96
    }
  }
  __syncthreads();

  // ---- compute: 8x8 register tile per thread ----
  const int m0 = (tid >> 4) << 3;   // 0..120
  const int n0 = (tid & 15) << 3;   // 0..120
  const int cb = n0 + ((n0 >> 3) << 2);
  float acc[8][8];
#pragma unroll
  for (int i = 0; i < 8; ++i)
#pragma unroll
    for (int j = 0; j < 8; ++j) acc[i][j] = 0.f;

  for (int k = 0; k < 64; ++k) {
    float4 a0 = *(const float4*)&At[k][m0];
    float4 a1 = *(const float4*)&At[k][m0 + 4];
    float4 b0 = *(const float4*)&Bsm[k][cb];
    float4 b1 = *(const float4*)&Bsm[k][cb + 4];
    float am[8] = {a0.x, a0.y, a0.z, a0.w, a1.x, a1.y, a1.z, a1.w};
    float bn[8] = {b0.x, b0.y, b0.z, b0.w, b1.x, b1.y, b1.z, b1.w};
#pragma unroll
    for (int i = 0; i < 8; ++i)
#pragma unroll
      for (int j = 0; j < 8; ++j) acc[i][j] += am[i] * bn[j];
  }

  // ---- epilogue: route quadrants (uniform per thread) ----
  if (m0 < 64) {
    if (n0 < 64) {
      // G[t][kd] = Q[t][kd]*exp(cs[t]) - PW
#pragma unroll
      for (int i = 0; i < 8; ++i) {
        int t = m0 + i;
        float ee = __expf(cbuf[(size_t)u * 64 + t]);
        const float* Qr = mix + (size_t)(t0g + t) * 3072 + hk * 64 + n0;
        float4 q0 = *(const float4*)(Qr);
        float4 q1 = *(const float4*)(Qr + 4);
        float4 g0 = {q0.x * ee - acc[i][0], q0.y * ee - acc[i][1],
                     q0.z * ee - acc[i][2], q0.w * ee - acc[i][3]};
        float4 g1 = {q1.x * ee - acc[i][4], q1.y * ee - acc[i][5],
                     q1.z * ee - acc[i][6], q1.w * ee - acc[i][7]};
        float* dst = Wbuf + (size_t)u * 4096 + t * 64 + n0;
        *(float4*)dst = g0; *(float4*)(dst + 4) = g1;
      }
    } else {
#pragma unroll
      for (int i = 0; i < 8; ++i) {
        float* dst = Rbuf + (size_t)u * 4096 + (m0 + i) * 64 + (n0 - 64);
        float4 r0 = {acc[i][0], acc[i][1], acc[i][2], acc[i][3]};
        float4 r1 = {acc[i][4], acc[i][5], acc[i][6], acc[i][7]};
        *(float4*)dst = r0; *(float4*)(dst + 4) = r1;
      }
    }
  } else {
    if (n0 < 64) {
#pragma unroll
      for (int i = 0; i < 8; ++i) {
        float* dst = Hbuf + (size_t)u * 4096 + (m0 - 64 + i) * 64 + n0;
        float4 h0 = {acc[i][0], acc[i][1], acc[i][2], acc[i][3]};
        float4 h1 = {acc[i][4], acc[i][5], acc[i][6], acc[i][7]};
        *(float4*)dst = h0; *(float4*)(dst + 4) = h1;
      }
    } else {
#pragma unroll
      for (int i = 0; i < 8; ++i) {
        float* dst = Pbuf + (size_t)u * 4096 + (m0 - 64 + i) * 64 + (n0 - 64);
        float4 k0v = {acc[i][0], acc[i][1], acc[i][2], acc[i][3]};
        float4 k1v = {acc[i][4], acc[i][5], acc[i][6], acc[i][7]};
        *(float4*)dst = k0v; *(float4*)(dst + 4) = k1v;
      }
    }
  }
}

// ---------------- chunked serial scan (v5: 512 thr, 2 cols/thread) ------------
__global__ __launch_bounds__(512) void chunk_scan_kernel(
    const float* __restrict__ Gbuf, const float* __restrict__ Hbuf,
    const float* __restrict__ ORbuf, const float* __restrict__ KRbuf,
    const float* __restrict__ cbuf, float* __restrict__ o) {
  __shared__ float Gs[64][68], Hs[64][68];
  __shared__ float St[16][68];

  const int bid = blockIdx.x;
  const int vs = bid & 3, hv = (bid >> 2) & 31, b = bid >> 7;
  const int bh = b * 32 + hv;
  const int ubase = bh * 16;
  const int tid = threadIdx.x;
  const int tr = tid >> 3, q8 = tid & 7;
  const int c0 = q8 * 2, c1 = q8 * 2 + 1;

  // zero S^T state (16*68 = 1088 floats)
  for (int i = tid; i < 16 * 68; i += 512) (&St[0][0])[i] = 0.f;

  float4 GN[2], HN[2];
  float2 ORn, KRn;
  float e63n = 0.f;

#define ISSUE(ch)                                                               \
  {                                                                             \
    size_t uu = (size_t)(ubase + (ch));                                         \
    _Pragma("unroll") for (int i = 0; i < 2; ++i) {                             \
      GN[i] = ((const float4*)(Gbuf + uu * 4096))[tid + 512 * i];               \
      HN[i] = ((const float4*)(Hbuf + uu * 4096))[tid + 512 * i];               \
    }                                                                           \
    ORn = *(const float2*)(ORbuf + uu * 4096 + tr * 64 + vs * 16 + q8 * 2);     \
    KRn = *(const float2*)(KRbuf + uu * 4096 + tr * 64 + vs * 16 + q8 * 2);     \
    e63n = cbuf[uu * 64 + 63];                                                  \
  }

#define COMMIT()                                                                \
  {                                                                             \
    _Pragma("unroll") for (int i = 0; i < 2; ++i) {                             \
      int flat = (tid + 512 * i) * 4;                                           \
      int rr = flat >> 6, cc = flat & 63;                                       \
      *(float4*)&Gs[rr][cc] = GN[i];                                            \
      *(float4*)&Hs[rr][cc] = HN[i];                                            \
    }                                                                           \
  }

  ISSUE(0);
  COMMIT();
  float2 ORv = ORn, KRv = KRn;
  float e63 = __expf(e63n);
  __syncthreads();

  for (int c = 0; c < 16; ++c) {
    if (c < 15) ISSUE(c + 1);
    float op0 = ORv.x, op1 = ORv.y, sn0 = KRv.x, sn1 = KRv.y;
    float sold0 = St[c0][tr], sold1 = St[c1][tr];
#pragma unroll
    for (int i = 0; i < 16; ++i) {
      float4 g4 = *(const float4*)&Gs[tr][i * 4];
      float4 h4 = *(const float4*)&Hs[tr][i * 4];
      float4 sa = *(const float4*)&St[c0][i * 4];
      float4 sb = *(const float4*)&St[c1][i * 4];
      op0 += g4.x * sa.x + g4.y * sa.y + g4.z * sa.z + g4.w * sa.w;
      op1 += g4.x * sb.x + g4.y * sb.y + g4.z * sb.z + g4.w * sb.w;
      sn0 -= h4.x * sa.x + h4.y * sa.y + h4.z * sa.z + h4.w * sa.w;
      sn1 -= h4.x * sb.x + h4.y * sb.y + h4.z * sb.z + h4.w * sb.w;
    }
    *(float2*)&o[((size_t)(bh * 4 + vs) * 1024 + c * 64 + tr) * 16 + q8 * 2] =
        (float2){op0, op1};
    float snew0 = sold0 * e63 + sn0;
    float snew1 = sold1 * e63 + sn1;
    __syncthreads();              // all G/H/S reads of this chunk done
    St[c0][tr] = snew0;
    St[c1][tr] = snew1;
    if (c < 15) {
      COMMIT();
      ORv = ORn; KRv = KRn; e63 = __expf(e63n);
    }
    __syncthreads();              // St + next G/H visible
  }
#undef ISSUE
#undef COMMIT
}

// ---------------- rmsnorm * norm_w * silu(z), -> bf16 ----------------
__global__ __launch_bounds__(256) void rms_gate_kernel(const float* __restrict__ o,
                                                       const float* __restrict__ qkvz,
                                                       const float* __restrict__ norm_w,
                                                       short* __restrict__ on) {
  int bid = blockIdx.x;            // (bh)*256 + tgroup
  int bh = bid >> 8;               // b*32+hv
  int tg = bid & 255;
  int b = bh >> 5, hv = bh & 31;
  int t = tg * 4 + (threadIdx.x >> 6);
  int d = threadIdx.x & 63;
  int bt = b * 1024 + t;
  int hk = hv >> 2, vp = hv & 3;
  float x = o[((size_t)(bh * 4 + (d >> 4)) * 1024 + t) * 16 + (d & 15)];
  float ss = x * x;
  ss += __shfl_xor(ss, 1);
  ss += __shfl_xor(ss, 2);
  ss += __shfl_xor(ss, 4);
  ss += __shfl_xor(ss, 8);
  ss += __shfl_xor(ss, 16);
  ss += __shfl_xor(ss, 32);
  float sc = rsqrtf(ss * (1.f / 64.f) + 1e-5f);
  float z = qkvz[(size_t)bt * 5184 + hk * 640 + 384 + vp * 64 + d];
  float val = x * sc * norm_w[d] * (z / (1.f + __expf(-z)));
  on[((size_t)bt * 32 + hv) * 64 + d] = f2bf(val);
}

// ---------------- launch ----------------
extern "C" void kernel_launch(void* const* d_in, const int* in_sizes, int n_in,
                              void* d_out, int out_size, void* d_ws, size_t ws_size,
                              hipStream_t stream) {
  const float* hidden = (const float*)d_in[0];
  const float* W_qkvz = (const float*)d_in[1];
  const float* W_ba = (const float*)d_in[2];
  const float* conv_w = (const float*)d_in[3];
  const float* dt_bias = (const float*)d_in[4];
  const float* A_log = (const float*)d_in[5];
  const float* norm_w = (const float*)d_in[6];
  const float* W_out = (const float*)d_in[7];
  float* out = (float*)d_out;

  char* ws = (char*)d_ws;
  short* A_bf = (short*)(ws + 0);                // 16,777,216 (dead after GEMM1)
  float* Hbuf = (float*)(ws + 0);                //   reused: H [1024][64][64]
  short* Wt1 = (short*)(ws + 16777216);          // 42,991,616  [5248][4096] (pad)
  short* Wt2 = (short*)(ws + 59768832);          // 16,777,216  [4096][2048]
  float* qkvz = (float*)(ws + 76546048);         // 42,467,328  [2048][5184]
  float* mix = (float*)(ws + 119013376);         // 25,165,824  [2048][3072]
  float* gbuf = (float*)(ws + 144179200);        //    262,144  [2048][32]
  float* beta = (float*)(ws + 144441344);        //    262,144
  float* o = (float*)(ws + 144703488);           // 16,777,216  [256][1024][16]
  short* on = (short*)(ws + 161480704);          //  8,388,608  [2048][2048]
  float* Wbuf = (float*)(ws + 169869312);        // 16,777,216  W -> G (in place)
  float* Pbuf = (float*)(ws + 186646528);        // 16,777,216  P -> KR (in place)
  float* Rbuf = (float*)(ws + 203423744);        // 16,777,216  R -> OR (in place)
  float* cbuf = (float*)(ws + 220200960);        //    262,144  [1024][64]

  to_bf16_kernel<<<8192, 256, 0, stream>>>(hidden, A_bf);
  transpose_w1<<<dim3(164, 128), 256, 0, stream>>>(W_qkvz, W_ba, Wt1);
  transpose_w2<<<dim3(128, 64), 256, 0, stream>>>(W_out, Wt2);
  // GEMM1: 16x41 = 656 blocks (r6 config, measured best of the family)
  gemm128p<true><<<656, 256, 0, stream>>>(A_bf, Wt1, qkvz, 5184, 4096, 16);
  conv_kernel<<<2048, 256, 0, stream>>>(qkvz, conv_w, dt_bias, A_log, mix, gbuf, beta);
  precompute_kernel<<<1024, 256, 0, stream>>>(mix, gbuf, beta, Wbuf, Pbuf, Rbuf, cbuf);
  precompute2_kernel<<<1024, 256, 0, stream>>>(mix, cbuf, Wbuf, Pbuf, Rbuf, Hbuf);
  chunk_scan_kernel<<<256, 512, 0, stream>>>(Wbuf, Hbuf, Rbuf, Pbuf, cbuf, o);
  rms_gate_kernel<<<16384, 256, 0, stream>>>(o, qkvz, norm_w, on);
  // GEMM2: 16x32 = 512 blocks = exactly 2/CU.
  gemm128p<false><<<512, 256, 0, stream>>>(on, Wt2, out, 4096, 2048, 16);
}

// Round 10
// 522.482 us; speedup vs baseline: 1.0658x; 1.0259x over previous
//
#include <hip/hip_runtime.h>
#include <hip/hip_bf16.h>
#include <cstdint>
#include <cstddef>

// ---------------- constants ----------------
// B=2 T=1024 H=4096 HK=8 HV=32 DK=64 DV=64 VPK=4
// GEMM1: A[2048][4096] * Wt1[5248(pad 5184)][4096]^T -> qkvz[2048][5184]
// GEMM2: on[2048][2048] * Wt2[4096][2048]^T -> out[2048][4096] (fp32)
// Both: gemm128p (r6 config: 4 waves, 3-buffer, counted vmcnt, XCD swizzle)
// Scan: O = OR + G@S, S' = e63*S + KR - H@S  (G,H,OR,KR from precompute2)

typedef __attribute__((ext_vector_type(8))) short short8;
typedef __attribute__((ext_vector_type(4))) float f32x4;

__device__ __forceinline__ short f2bf(float f) {
  union { float f; unsigned u; } x; x.f = f;
  unsigned r = x.u + 0x7fffu + ((x.u >> 16) & 1u);
  return (short)(r >> 16);
}

__device__ __forceinline__ void gl_lds16(const short* g, short* l) {
  __builtin_amdgcn_global_load_lds(
      (const __attribute__((address_space(1))) void*)g,
      (__attribute__((address_space(3))) void*)l, 16, 0, 0);
}

// ---------------- merged prep: fp32->bf16 cast + both weight transposes --------
// Block-uniform branch on blockIdx range; saves 2 launches + serialization.
__global__ __launch_bounds__(256) void prep_kernel(const float* __restrict__ hidden,
                                                   const float* __restrict__ Wq,
                                                   const float* __restrict__ Wba,
                                                   const float* __restrict__ Wo,
                                                   short* __restrict__ A_bf,
                                                   short* __restrict__ Wt1,
                                                   short* __restrict__ Wt2) {
  __shared__ float tile[32][33];
  const int bid = blockIdx.x;
  const int t = threadIdx.x;
  if (bid < 8192) {
    // ---- to_bf16: hidden -> A_bf, one float4/thread ----
    int i = bid * 256 + t;
    float4 v = ((const float4*)hidden)[i];
    ushort4 r;
    r.x = (unsigned short)f2bf(v.x);
    r.y = (unsigned short)f2bf(v.y);
    r.z = (unsigned short)f2bf(v.z);
    r.w = (unsigned short)f2bf(v.w);
    ((ushort4*)A_bf)[i] = r;
    return;
  }
  int r = t >> 5;
  int c = t & 31;
  if (bid < 8192 + 20992) {
    // ---- transpose W_qkvz|W_ba -> Wt1[n][k] (164 x 128 tiles) ----
    int b2 = bid - 8192;
    int n0 = (b2 % 164) * 32;
    int k0 = (b2 / 164) * 32;
#pragma unroll
    for (int i = 0; i < 4; ++i) {
      int kl = r + i * 8;
      int n = n0 + c;
      float v = 0.f;
      if (n < 5120) v = Wq[(size_t)(k0 + kl) * 5120 + n];
      else if (n < 5184) v = Wba[(size_t)(k0 + kl) * 64 + (n - 5120)];
      tile[kl][c] = v;
    }
    __syncthreads();
#pragma unroll
    for (int i = 0; i < 4; ++i) {
      int nl = r + i * 8;
      Wt1[(size_t)(n0 + nl) * 4096 + k0 + c] = f2bf(tile[c][nl]);
    }
    return;
  }
  // ---- transpose W_out -> Wt2[n][k] (128 x 64 tiles) ----
  int b3 = bid - 29184;
  int n0 = (b3 % 128) * 32;
  int k0 = (b3 / 128) * 32;
#pragma unroll
  for (int i = 0; i < 4; ++i) {
    int kl = r + i * 8;
    tile[kl][c] = Wo[(size_t)(k0 + kl) * 4096 + n0 + c];
  }
  __syncthreads();
#pragma unroll
  for (int i = 0; i < 4; ++i) {
    int nl = r + i * 8;
    Wt2[(size_t)(n0 + nl) * 2048 + k0 + c] = f2bf(tile[c][nl]);
  }
}

// ---------------- 128x128 pipelined bf16 MFMA GEMM (3-stage, counted vmcnt) ----
// Round-6 verified config: 4 waves (2Mx2N), 48 KiB LDS -> 3 blocks/CU,
// counted vmcnt(4), 0 bank conflicts, bijective XCD swizzle.  At the m97-family
// MfmaUtil ceiling (~34-37%); r7/r8 variants regressed -> keep.
template <bool GUARD_N>
__global__ __launch_bounds__(256) void gemm128p(const short* __restrict__ A,
                                                const short* __restrict__ Bt,
                                                float* __restrict__ C,
                                                int N, int K, int MT) {
  __shared__ __align__(16) short As[3 * 4096];
  __shared__ __align__(16) short Bs[3 * 4096];
  const int tid = threadIdx.x;
  const int w = tid >> 6, lane = tid & 63;
  const int wm = w >> 1, wn = w & 1;

  const int nwg = gridDim.x;
  const int bid = blockIdx.x;
  const int swz = (bid & 7) * (nwg >> 3) + (bid >> 3);
  const int m0 = (swz % MT) * 128;
  const int n0 = (swz / MT) * 128;

  const int p0 = w * 64 + lane;
  const int rp0 = p0 >> 3, q0 = p0 & 7;
  const int mm0 = q0 ^ (rp0 & 7);
  const int srow = rp0 * 2 + (mm0 >> 2);     // 0..63 (round1 = +64)
  const int scol = (mm0 & 3) << 3;           // elem offset 0/8/16/24
  const short* Ag = A + (size_t)(m0 + srow) * K + scol;
  const short* Bg = Bt + (size_t)(n0 + srow) * K + scol;
  const size_t rstep = (size_t)64 * K;

  const int fr = lane & 15;
  const int s = lane >> 4;
  int aoff[4], boff[4];
#pragma unroll
  for (int i = 0; i < 4; ++i) {
    int row = wm * 64 + i * 16 + fr;
    int rp = row >> 1;
    int q = (((row & 1) << 2) | s) ^ (rp & 7);
    aoff[i] = (rp * 8 + q) * 8;
  }
#pragma unroll
  for (int j = 0; j < 4; ++j) {
    int row = wn * 64 + j * 16 + fr;
    int rp = row >> 1;
    int q = (((row & 1) << 2) | s) ^ (rp & 7);
    boff[j] = (rp * 8 + q) * 8;
  }

  f32x4 acc[4][4];
#pragma unroll
  for (int i = 0; i < 4; ++i)
#pragma unroll
    for (int j = 0; j < 4; ++j) acc[i][j] = (f32x4){0.f, 0.f, 0.f, 0.f};

  const int NKT = K >> 5;

#define STAGE_A(kt, bb)                                                \
  { const short* g = Ag + (size_t)(kt) * 32;                           \
    gl_lds16(g,         &As[(bb) * 4096 + w * 512]);                   \
    gl_lds16(g + rstep, &As[(bb) * 4096 + 2048 + w * 512]); }
#define STAGE_B(kt, bb)                                                \
  { const short* g = Bg + (size_t)(kt) * 32;                           \
    gl_lds16(g,         &Bs[(bb) * 4096 + w * 512]);                   \
    gl_lds16(g + rstep, &Bs[(bb) * 4096 + 2048 + w * 512]); }

  STAGE_A(0, 0); STAGE_B(0, 0);
  STAGE_A(1, 1); STAGE_B(1, 1);
  asm volatile("s_waitcnt vmcnt(4)" ::: "memory");
  __builtin_amdgcn_s_barrier();
  __builtin_amdgcn_sched_barrier(0);

  int bi = 0;
  for (int kt = 0; kt < NKT; ++kt) {
    int bi2 = bi - 1; if (bi2 < 0) bi2 = 2;   // (kt+2)%3
    const short* Ab = &As[bi * 4096];
    const short* Bb = &Bs[bi * 4096];
    short8 af[2], bf[4];
#pragma unroll
    for (int i = 0; i < 2; ++i) af[i] = *(const short8*)&Ab[aoff[i]];
#pragma unroll
    for (int j = 0; j < 4; ++j) bf[j] = *(const short8*)&Bb[boff[j]];
    if (kt + 2 < NKT) STAGE_A(kt + 2, bi2);
    __builtin_amdgcn_s_barrier();
    asm volatile("s_waitcnt lgkmcnt(0)" ::: "memory");
    __builtin_amdgcn_sched_barrier(0);
    __builtin_amdgcn_s_setprio(1);
#pragma unroll
    for (int i = 0; i < 2; ++i)
#pragma unroll
      for (int j = 0; j < 4; ++j)
        acc[i][j] = __builtin_amdgcn_mfma_f32_16x16x32_bf16(af[i], bf[j], acc[i][j], 0, 0, 0);
    __builtin_amdgcn_s_setprio(0);
    __builtin_amdgcn_sched_barrier(0);
#pragma unroll
    for (int i = 0; i < 2; ++i) af[i] = *(const short8*)&Ab[aoff[i + 2]];
    if (kt + 2 < NKT) STAGE_B(kt + 2, bi2);
    if (kt < NKT - 2) { asm volatile("s_waitcnt vmcnt(4)" ::: "memory"); }
    else              { asm volatile("s_waitcnt vmcnt(0)" ::: "memory"); }
    __builtin_amdgcn_s_barrier();
    asm volatile("s_waitcnt lgkmcnt(0)" ::: "memory");
    __builtin_amdgcn_sched_barrier(0);
    __builtin_amdgcn_s_setprio(1);
#pragma unroll
    for (int i = 0; i < 2; ++i)
#pragma unroll
      for (int j = 0; j < 4; ++j)
        acc[i + 2][j] = __builtin_amdgcn_mfma_f32_16x16x32_bf16(af[i], bf[j], acc[i + 2][j], 0, 0, 0);
    __builtin_amdgcn_s_setprio(0);
    __builtin_amdgcn_sched_barrier(0);
    __builtin_amdgcn_s_barrier();
    ++bi; if (bi == 3) bi = 0;
  }
#undef STAGE_A
#undef STAGE_B

  const int rbase = (lane >> 4) << 2;
#pragma unroll
  for (int i = 0; i < 4; ++i) {
#pragma unroll
    for (int j = 0; j < 4; ++j) {
      int col = n0 + wn * 64 + j * 16 + fr;
      if (GUARD_N && col >= N) continue;
      int row = m0 + wm * 64 + i * 16 + rbase;
#pragma unroll
      for (int r = 0; r < 4; ++r)
        C[(size_t)(row + r) * N + col] = acc[i][j][r];
    }
  }
}

// ---------------- conv(4-tap causal) + silu + l2norm(q,k) + fused gates ---------
// Vectorized: each thread handles 4 consecutive channels (float4 loads for
// qkvz taps and conv_w; tap-validity branch is block-uniform).  G13: scalar
// bf16/fp32 loads are ~2x slower -- this cuts 12K scalar loads to 3K float4.
__global__ __launch_bounds__(256) void conv_kernel(const float* __restrict__ qkvz,
                                                   const float* __restrict__ conv_w,
                                                   const float* __restrict__ dt_bias,
                                                   const float* __restrict__ A_log,
                                                   float* __restrict__ mix,
                                                   float* __restrict__ gb,
                                                   float* __restrict__ beta) {
  __shared__ float sq[1024];
  __shared__ float scale[16];
  int bt = blockIdx.x;       // b*1024 + t
  int t = bt & 1023;
  int tid = threadIdx.x;
#pragma unroll
  for (int it = 0; it < 3; ++it) {
    int c0 = (tid + it * 256) * 4;   // 0..3068, 4-aligned; group shares mapping
    int col;
    if (c0 < 512) {
      col = (c0 >> 6) * 640 + (c0 & 63);
    } else if (c0 < 1024) {
      int c2 = c0 - 512;
      col = (c2 >> 6) * 640 + 64 + (c2 & 63);
    } else {
      int c3 = c0 - 1024;
      int hv = c3 >> 6;
      col = (hv >> 2) * 640 + 128 + (hv & 3) * 64 + (c3 & 63);
    }
    float cwa[4][4];
#pragma unroll
    for (int e = 0; e < 4; ++e) {
      float4 w4 = *(const float4*)(conv_w + (size_t)(c0 + e) * 4);
      cwa[e][0] = w4.x; cwa[e][1] = w4.y; cwa[e][2] = w4.z; cwa[e][3] = w4.w;
    }
    float4 acc = {0.f, 0.f, 0.f, 0.f};
#pragma unroll
    for (int j = 0; j < 4; ++j) {
      if (t - 3 + j >= 0) {   // block-uniform branch
        float4 qv = *(const float4*)(qkvz + (size_t)(bt - 3 + j) * 5184 + col);
        acc.x += qv.x * cwa[0][j];
        acc.y += qv.y * cwa[1][j];
        acc.z += qv.z * cwa[2][j];
        acc.w += qv.w * cwa[3][j];
      }
    }
    float4 sv;
    sv.x = acc.x / (1.f + __expf(-acc.x));
    sv.y = acc.y / (1.f + __expf(-acc.y));
    sv.z = acc.z / (1.f + __expf(-acc.z));
    sv.w = acc.w / (1.f + __expf(-acc.w));
    if (c0 < 1024)
      *(float4*)&sq[c0] = sv;
    else
      *(float4*)(mix + (size_t)bt * 3072 + c0) = sv;
  }
  // fused gate computation: one thread per hv
  if (tid < 32) {
    int hv2 = tid;
    int hk2 = hv2 >> 2, vp = hv2 & 3;
    const float* row = qkvz + (size_t)bt * 5184 + 5120 + hk2 * 8;
    float bv = row[vp];
    float av = row[4 + vp];
    float x = av + dt_bias[hv2];
    float sp = (x > 20.f) ? x : log1pf(expf(x));
    gb[(size_t)bt * 32 + hv2] = -expf(A_log[hv2]) * sp;   // log-decay g_t (<= 0)
    beta[(size_t)bt * 32 + hv2] = 1.f / (1.f + expf(-bv));
  }
  __syncthreads();
  int g = tid >> 4, l = tid & 15;
  float p = 0.f;
#pragma unroll
  for (int i = 0; i < 4; ++i) {
    float v = sq[g * 64 + l * 4 + i];
    p += v * v;
  }
  p += __shfl_xor(p, 1);
  p += __shfl_xor(p, 2);
  p += __shfl_xor(p, 4);
  p += __shfl_xor(p, 8);
  if (l == 0) scale[g] = rsqrtf(p + 1e-6f);
  __syncthreads();
  {
    int c0 = tid * 4;   // 0..1020
    float s = scale[c0 >> 6] * ((c0 < 512) ? 0.125f : 1.f);  // q gets DK^-0.5
    float4 v = *(const float4*)&sq[c0];
    v.x *= s; v.y *= s; v.z *= s; v.w *= s;
    *(float4*)(mix + (size_t)bt * 3072 + c0) = v;
  }
}

// ---------------- chunked delta-rule precompute (stage 1, 4x4-tiled matmuls) ----
__global__ __launch_bounds__(256) void precompute_kernel(
    const float* __restrict__ mix, const float* __restrict__ gbuf,
    const float* __restrict__ betab, float* __restrict__ Wbuf,
    float* __restrict__ Pbuf, float* __restrict__ Rbuf, float* __restrict__ cbuf) {
  __shared__ float Kt[64][68];   // K col-major: Kt[d][t]; later K' row-major scaled
  __shared__ float Vb[64][68];   // V row-major
  __shared__ float AM[64][68];   // A; later Q col-major
  __shared__ float Mm[64][68];   // (I+A)^{-1}
  __shared__ float Tb[16][17];
  __shared__ float cs[64], bb[64];

  const int u = blockIdx.x;
  const int chunk = u & 15, hv = (u >> 4) & 31, b = u >> 9;
  const int hk = hv >> 2;
  const int t0g = b * 1024 + chunk * 64;
  const int tid = threadIdx.x;
  const int tr = tid >> 2, q4 = tid & 3;
  const int r4 = tid >> 4, c4 = tid & 15;   // 4x4 tile: rows r4*4+i, cols c4*4+j

  {
    const float* mrow = mix + (size_t)(t0g + tr) * 3072;
#pragma unroll
    for (int e = 0; e < 4; ++e) {
      int c0 = q4 * 16 + e * 4;
      float4 kv = *(const float4*)(mrow + 512 + hk * 64 + c0);
      Kt[c0 + 0][tr] = kv.x; Kt[c0 + 1][tr] = kv.y;
      Kt[c0 + 2][tr] = kv.z; Kt[c0 + 3][tr] = kv.w;
      *(float4*)&Vb[tr][c0] = *(const float4*)(mrow + 1024 + hv * 64 + c0);
    }
  }
  if (tid < 64) {
    cs[tid] = gbuf[(size_t)(t0g + tid) * 32 + hv];
    bb[tid] = betab[(size_t)(t0g + tid) * 32 + hv];
  }
  __syncthreads();
  for (int off = 1; off < 64; off <<= 1) {
    float v = 0.f;
    if (tid < 64 && tid >= off) v = cs[tid - off];
    __syncthreads();
    if (tid < 64) cs[tid] += v;
    __syncthreads();
  }
  if (tid < 64) cbuf[(size_t)u * 64 + tid] = cs[tid];

  // ---- A = tril(K K^T, -1) .* bb_r .* exp(cs_r - cs_s), 4x4 tile/thread ----
  {
    float acc[4][4];
#pragma unroll
    for (int i = 0; i < 4; ++i)
#pragma unroll
      for (int j = 0; j < 4; ++j) acc[i][j] = 0.f;
    for (int d = 0; d < 64; ++d) {
      float4 a4 = *(const float4*)&Kt[d][r4 * 4];
      float4 b4 = *(const float4*)&Kt[d][c4 * 4];
      float av[4] = {a4.x, a4.y, a4.z, a4.w};
      float bv[4] = {b4.x, b4.y, b4.z, b4.w};
#pragma unroll
      for (int i = 0; i < 4; ++i)
#pragma unroll
        for (int j = 0; j < 4; ++j) acc[i][j] += av[i] * bv[j];
    }
    float4 cc = *(const float4*)&cs[c4 * 4];
    float ccv[4] = {cc.x, cc.y, cc.z, cc.w};
#pragma unroll
    for (int i = 0; i < 4; ++i) {
      int row = r4 * 4 + i;
      float bt_ = bb[row], ct_ = cs[row];
      float ov[4];
#pragma unroll
      for (int j = 0; j < 4; ++j) {
        int sc = c4 * 4 + j;
        ov[j] = (sc < row) ? bt_ * acc[i][j] * __expf(ct_ - ccv[j]) : 0.f;
      }
      float4 o4 = {ov[0], ov[1], ov[2], ov[3]};
      *(float4*)&AM[row][c4 * 4] = o4;
    }
  }
  __syncthreads();

  for (int i = tid; i < 64 * 68; i += 256) (&Mm[0][0])[i] = 0.f;
  __syncthreads();
  if (tid < 64) {
    int blk = tid >> 4, j = tid & 15, base = blk * 16;
    Mm[base][base + j] = (j == 0) ? 1.f : 0.f;
    for (int r = 1; r < 16; ++r) {
      float sum = 0.f;
      for (int s = 0; s < r; ++s) sum += AM[base + r][base + s] * Mm[base + s][base + j];
      Mm[base + r][base + j] = ((r == j) ? 1.f : 0.f) - sum;
    }
  }
  __syncthreads();
  for (int d = 1; d < 4; ++d) {
    for (int j = 0; j + d < 4; ++j) {
      int i = j + d;
      int r = tid >> 4, c = tid & 15;
      float tsum = 0.f;
      for (int kb = j; kb < i; ++kb)
        for (int uu = 0; uu < 16; ++uu)
          tsum += AM[i * 16 + r][kb * 16 + uu] * Mm[kb * 16 + uu][j * 16 + c];
      Tb[r][c] = tsum;
      __syncthreads();
      float msum = 0.f;
      for (int uu = 0; uu < 16; ++uu)
        msum += Mm[i * 16 + r][i * 16 + uu] * Tb[uu][c];
      __syncthreads();
      Mm[i * 16 + r][j * 16 + c] = -msum;
      __syncthreads();
    }
  }

  {
    const float* mrow = mix + (size_t)(t0g + tr) * 3072 + hk * 64;
#pragma unroll
    for (int e = 0; e < 4; ++e) {
      int c0 = q4 * 16 + e * 4;
      float4 qv = *(const float4*)(mrow + c0);
      AM[c0 + 0][tr] = qv.x; AM[c0 + 1][tr] = qv.y;
      AM[c0 + 2][tr] = qv.z; AM[c0 + 3][tr] = qv.w;
    }
  }
  __syncthreads();

  // ---- P = tril(Q K^T, 0) .* exp(cs_t - cs_s), 4x4 tile/thread ----
  {
    float acc[4][4];
#pragma unroll
    for (int i = 0; i < 4; ++i)
#pragma unroll
      for (int j = 0; j < 4; ++j) acc[i][j] = 0.f;
    for (int d = 0; d < 64; ++d) {
      float4 a4 = *(const float4*)&AM[d][r4 * 4];   // Q col-major
      float4 b4 = *(const float4*)&Kt[d][c4 * 4];
      float av[4] = {a4.x, a4.y, a4.z, a4.w};
      float bv[4] = {b4.x, b4.y, b4.z, b4.w};
#pragma unroll
      for (int i = 0; i < 4; ++i)
#pragma unroll
        for (int j = 0; j < 4; ++j) acc[i][j] += av[i] * bv[j];
    }
    float4 cc = *(const float4*)&cs[c4 * 4];
    float ccv[4] = {cc.x, cc.y, cc.z, cc.w};
#pragma unroll
    for (int i = 0; i < 4; ++i) {
      int row = r4 * 4 + i;
      float ct_ = cs[row];
      float pv[4];
#pragma unroll
      for (int j = 0; j < 4; ++j) {
        int sc = c4 * 4 + j;
        pv[j] = (sc <= row) ? acc[i][j] * __expf(ct_ - ccv[j]) : 0.f;
      }
      float4 p4 = {pv[0], pv[1], pv[2], pv[3]};
      *(float4*)&Pbuf[(size_t)u * 4096 + row * 64 + c4 * 4] = p4;
    }
  }
  __syncthreads();

  {
    float vals[16];
#pragma unroll
    for (int j = 0; j < 16; ++j) vals[j] = Kt[q4 * 16 + j][tr];
    float sc = bb[tr] * __expf(cs[tr]);
    __syncthreads();
#pragma unroll
    for (int j = 0; j < 16; ++j) Kt[tr][q4 * 16 + j] = vals[j] * sc;
  }
  __syncthreads();

  // ---- fused W = Mm @ K', R = Mm @ diag(bb) @ V, 4x4 tiles, s unrolled x4 ----
  {
    float aw[4][4], ar[4][4];
#pragma unroll
    for (int i = 0; i < 4; ++i)
#pragma unroll
      for (int j = 0; j < 4; ++j) { aw[i][j] = 0.f; ar[i][j] = 0.f; }
    for (int s0 = 0; s0 < 64; s0 += 4) {
      float4 am[4];
#pragma unroll
      for (int i = 0; i < 4; ++i) am[i] = *(const float4*)&Mm[r4 * 4 + i][s0];
      float4 bq = *(const float4*)&bb[s0];
      float bbv[4] = {bq.x, bq.y, bq.z, bq.w};
      float kv[4][4], vv[4][4];
#pragma unroll
      for (int uu = 0; uu < 4; ++uu) {
        float4 k4 = *(const float4*)&Kt[s0 + uu][c4 * 4];
        float4 v4 = *(const float4*)&Vb[s0 + uu][c4 * 4];
        kv[uu][0] = k4.x; kv[uu][1] = k4.y; kv[uu][2] = k4.z; kv[uu][3] = k4.w;
        vv[uu][0] = v4.x; vv[uu][1] = v4.y; vv[uu][2] = v4.z; vv[uu][3] = v4.w;
      }
#pragma unroll
      for (int i = 0; i < 4; ++i) {
        float amv[4] = {am[i].x, am[i].y, am[i].z, am[i].w};
#pragma unroll
        for (int uu = 0; uu < 4; ++uu) {
          float mw = amv[uu];
          float mr = mw * bbv[uu];
#pragma unroll
          for (int j = 0; j < 4; ++j) {
            aw[i][j] += mw * kv[uu][j];
            ar[i][j] += mr * vv[uu][j];
          }
        }
      }
    }
#pragma unroll
    for (int i = 0; i < 4; ++i) {
      int row = r4 * 4 + i;
      float4 w4 = {aw[i][0], aw[i][1], aw[i][2], aw[i][3]};
      float4 rr = {ar[i][0], ar[i][1], ar[i][2], ar[i][3]};
      *(float4*)&Wbuf[(size_t)u * 4096 + row * 64 + c4 * 4] = w4;
      *(float4*)&Rbuf[(size_t)u * 4096 + row * 64 + c4 * 4] = rr;
    }
  }
}

// ---------------- precompute2: batched [P;Kt] @ [W|R] -> G,H,OR,KR (fp32) -------
__global__ __launch_bounds__(256) void precompute2_kernel(
    const float* __restrict__ mix, const float* __restrict__ cbuf,
    float* __restrict__ Wbuf, float* __restrict__ Pbuf, float* __restrict__ Rbuf,
    float* __restrict__ Hbuf) {
  __shared__ float At[64][132];
  __shared__ float Bsm[64][188];

  const int u = blockIdx.x;
  const int chunk = u & 15, hv = (u >> 4) & 31, b = u >> 9;
  const int hk = hv >> 2;
  const int t0g = b * 1024 + chunk * 64;
  const int tid = threadIdx.x;
  const int tr = tid >> 2, q4 = tid & 3;

  const float c63 = cbuf[(size_t)u * 64 + 63];
  const float csr = cbuf[(size_t)u * 64 + tr];
  const float sKv = __expf(c63 - csr);

  // ---- stage: P^T into At[0:64][m<64], scaled-K into At[t][64+kd] ----
  {
    const float* Pr = Pbuf + (size_t)u * 4096 + tr * 64;
#pragma unroll
    for (int e = 0; e < 4; ++e) {
      int k0 = q4 * 16 + e * 4;
      float4 p4 = *(const float4*)(Pr + k0);
      At[k0 + 0][tr] = p4.x; At[k0 + 1][tr] = p4.y;
      At[k0 + 2][tr] = p4.z; At[k0 + 3][tr] = p4.w;
    }
    const float* Kr = mix + (size_t)(t0g + tr) * 3072 + 512 + hk * 64;
#pragma unroll
    for (int e = 0; e < 4; ++e) {
      int n = q4 * 16 + e * 4;
      float4 k4 = *(const float4*)(Kr + n);
      float4 o4 = {k4.x * sKv, k4.y * sKv, k4.z * sKv, k4.w * sKv};
      *(float4*)&At[tr][64 + n] = o4;
    }
  }
  // ---- stage: B rows (W | R), swizzled ----
  {
    const float* Wr = Wbuf + (size_t)u * 4096 + tr * 64;
    const float* Rr = Rbuf + (size_t)u * 4096 + tr * 64;
#pragma unroll
    for (int e = 0; e < 4; ++e) {
      int n = q4 * 16 + e * 4;
      int cp = n + ((n >> 3) << 2);
      *(float4*)&Bsm[tr][cp] = *(const float4*)(Wr + n);
      *(float4*)&Bsm[tr][cp + 96] = *(const float4*)(Rr + n);  // col'(64+n)=col'(n)+96
    }
  }
  __syncthreads();

  // ---- compute: 8x8 register tile per thread ----
  const int m0 = (tid >> 4) << 3;   // 0..120
  const int n0 = (tid & 15) << 3;   // 0..120
  const int cb = n0 + ((n0 >> 3) << 2);
  float acc[8][8];
#pragma unroll
  for (int i = 0; i < 8; ++i)
#pragma unroll
    for (int j = 0; j < 8; ++j) acc[i][j] = 0.f;

  for (int k = 0; k < 64; ++k) {
    float4 a0 = *(const float4*)&At[k][m0];
    float4 a1 = *(const float4*)&At[k][m0 + 4];
    float4 b0 = *(const float4*)&Bsm[k][cb];
    float4 b1 = *(const float4*)&Bsm[k][cb + 4];
    float am[8] = {a0.x, a0.y, a0.z, a0.w, a1.x, a1.y, a1.z, a1.w};
    float bn[8] = {b0.x, b0.y, b0.z, b0.w, b1.x, b1.y, b1.z, b1.w};
#pragma unroll
    for (int i = 0; i < 8; ++i)
#pragma unroll
      for (int j = 0; j < 8; ++j) acc[i][j] += am[i] * bn[j];
  }

  // ---- epilogue: route quadrants (uniform per thread) ----
  if (m0 < 64) {
    if (n0 < 64) {
      // G[t][kd] = Q[t][kd]*exp(cs[t]) - PW
#pragma unroll
      for (int i = 0; i < 8; ++i) {
        int t = m0 + i;
        float ee = __expf(cbuf[(size_t)u * 64 + t]);
        const float* Qr = mix + (size_t)(t0g + t) * 3072 + hk * 64 + n0;
        float4 q0 = *(const float4*)(Qr);
        float4 q1 = *(const float4*)(Qr + 4);
        float4 g0 = {q0.x * ee - acc[i][0], q0.y * ee - acc[i][1],
                     q0.z * ee - acc[i][2], q0.w * ee - acc[i][3]};
        float4 g1 = {q1.x * ee - acc[i][4], q1.y * ee - acc[i][5],
                     q1.z * ee - acc[i][6], q1.w * ee - acc[i][7]};
        float* dst = Wbuf + (size_t)u * 4096 + t * 64 + n0;
        *(float4*)dst = g0; *(float4*)(dst + 4) = g1;
      }
    } else {
#pragma unroll
      for (int i = 0; i < 8; ++i) {
        float* dst = Rbuf + (size_t)u * 4096 + (m0 + i) * 64 + (n0 - 64);
        float4 r0 = {acc[i][0], acc[i][1], acc[i][2], acc[i][3]};
        float4 r1 = {acc[i][4], acc[i][5], acc[i][6], acc[i][7]};
        *(float4*)dst = r0; *(float4*)(dst + 4) = r1;
      }
    }
  } else {
    if (n0 < 64) {
#pragma unroll
      for (int i = 0; i < 8; ++i) {
        float* dst = Hbuf + (size_t)u * 4096 + (m0 - 64 + i) * 64 + n0;
        float4 h0 = {acc[i][0], acc[i][1], acc[i][2], acc[i][3]};
        float4 h1 = {acc[i][4], acc[i][5], acc[i][6], acc[i][7]};
        *(float4*)dst = h0; *(float4*)(dst + 4) = h1;
      }
    } else {
#pragma unroll
      for (int i = 0; i < 8; ++i) {
        float* dst = Pbuf + (size_t)u * 4096 + (m0 - 64 + i) * 64 + (n0 - 64);
        float4 k0v = {acc[i][0], acc[i][1], acc[i][2], acc[i][3]};
        float4 k1v = {acc[i][4], acc[i][5], acc[i][6], acc[i][7]};
        *(float4*)dst = k0v; *(float4*)(dst + 4) = k1v;
      }
    }
  }
}

// ---------------- chunked serial scan (v5: 512 thr, 2 cols/thread) ------------
__global__ __launch_bounds__(512) void chunk_scan_kernel(
    const float* __restrict__ Gbuf, const float* __restrict__ Hbuf,
    const float* __restrict__ ORbuf, const float* __restrict__ KRbuf,
    const float* __restrict__ cbuf, float* __restrict__ o) {
  __shared__ float Gs[64][68], Hs[64][68];
  __shared__ float St[16][68];

  const int bid = blockIdx.x;
  const int vs = bid & 3, hv = (bid >> 2) & 31, b = bid >> 7;
  const int bh = b * 32 + hv;
  const int ubase = bh * 16;
  const int tid = threadIdx.x;
  const int tr = tid >> 3, q8 = tid & 7;
  const int c0 = q8 * 2, c1 = q8 * 2 + 1;

  // zero S^T state (16*68 = 1088 floats)
  for (int i = tid; i < 16 * 68; i += 512) (&St[0][0])[i] = 0.f;

  float4 GN[2], HN[2];
  float2 ORn, KRn;
  float e63n = 0.f;

#define ISSUE(ch)                                                               \
  {                                                                             \
    size_t uu = (size_t)(ubase + (ch));                                         \
    _Pragma("unroll") for (int i = 0; i < 2; ++i) {                             \
      GN[i] = ((const float4*)(Gbuf + uu * 4096))[tid + 512 * i];               \
      HN[i] = ((const float4*)(Hbuf + uu * 4096))[tid + 512 * i];               \
    }                                                                           \
    ORn = *(const float2*)(ORbuf + uu * 4096 + tr * 64 + vs * 16 + q8 * 2);     \
    KRn = *(const float2*)(KRbuf + uu * 4096 + tr * 64 + vs * 16 + q8 * 2);     \
    e63n = cbuf[uu * 64 + 63];                                                  \
  }

#define COMMIT()                                                                \
  {                                                                             \
    _Pragma("unroll") for (int i = 0; i < 2; ++i) {                             \
      int flat = (tid + 512 * i) * 4;                                           \
      int rr = flat >> 6, cc = flat & 63;                                       \
      *(float4*)&Gs[rr][cc] = GN[i];                                            \
      *(float4*)&Hs[rr][cc] = HN[i];                                            \
    }                                                                           \
  }

  ISSUE(0);
  COMMIT();
  float2 ORv = ORn, KRv = KRn;
  float e63 = __expf(e63n);
  __syncthreads();

  for (int c = 0; c < 16; ++c) {
    if (c < 15) ISSUE(c + 1);
    float op0 = ORv.x, op1 = ORv.y, sn0 = KRv.x, sn1 = KRv.y;
    float sold0 = St[c0][tr], sold1 = St[c1][tr];
#pragma unroll
    for (int i = 0; i < 16; ++i) {
      float4 g4 = *(const float4*)&Gs[tr][i * 4];
      float4 h4 = *(const float4*)&Hs[tr][i * 4];
      float4 sa = *(const float4*)&St[c0][i * 4];
      float4 sb = *(const float4*)&St[c1][i * 4];
      op0 += g4.x * sa.x + g4.y * sa.y + g4.z * sa.z + g4.w * sa.w;
      op1 += g4.x * sb.x + g4.y * sb.y + g4.z * sb.z + g4.w * sb.w;
      sn0 -= h4.x * sa.x + h4.y * sa.y + h4.z * sa.z + h4.w * sa.w;
      sn1 -= h4.x * sb.x + h4.y * sb.y + h4.z * sb.z + h4.w * sb.w;
    }
    *(float2*)&o[((size_t)(bh * 4 + vs) * 1024 + c * 64 + tr) * 16 + q8 * 2] =
        (float2){op0, op1};
    float snew0 = sold0 * e63 + sn0;
    float snew1 = sold1 * e63 + sn1;
    __syncthreads();              // all G/H/S reads of this chunk done
    St[c0][tr] = snew0;
    St[c1][tr] = snew1;
    if (c < 15) {
      COMMIT();
      ORv = ORn; KRv = KRn; e63 = __expf(e63n);
    }
    __syncthreads();              // St + next G/H visible
  }
#undef ISSUE
#undef COMMIT
}

// ---------------- rmsnorm * norm_w * silu(z), -> bf16 (vectorized) -------------
// 4096 blocks; block = one (b,hv) x 16 consecutive t; thread handles float4 of
// d.  Row reduction = 16-lane shfl group (xor masks 1..8 stay in-group).
__global__ __launch_bounds__(256) void rms_gate_kernel(const float* __restrict__ o,
                                                       const float* __restrict__ qkvz,
                                                       const float* __restrict__ norm_w,
                                                       short* __restrict__ on) {
  int bid = blockIdx.x;            // bh*64 + tg
  int bh = bid >> 6;               // b*32+hv
  int tg = bid & 63;
  int b = bh >> 5, hv = bh & 31;
  int r = threadIdx.x >> 4;        // 0..15 rows in block
  int d4 = threadIdx.x & 15;
  int t = tg * 16 + r;
  int d = d4 * 4;
  int bt = b * 1024 + t;
  int hk = hv >> 2, vp = hv & 3;
  float4 x4 = *(const float4*)&o[((size_t)(bh * 4 + (d >> 4)) * 1024 + t) * 16 + (d & 15)];
  float ss = x4.x * x4.x + x4.y * x4.y + x4.z * x4.z + x4.w * x4.w;
  ss += __shfl_xor(ss, 1);
  ss += __shfl_xor(ss, 2);
  ss += __shfl_xor(ss, 4);
  ss += __shfl_xor(ss, 8);
  float sc = rsqrtf(ss * (1.f / 64.f) + 1e-5f);
  float4 z4 = *(const float4*)&qkvz[(size_t)bt * 5184 + hk * 640 + 384 + vp * 64 + d];
  float4 w4 = *(const float4*)&norm_w[d];
  ushort4 out4;
  float v0 = x4.x * sc * w4.x * (z4.x / (1.f + __expf(-z4.x)));
  float v1 = x4.y * sc * w4.y * (z4.y / (1.f + __expf(-z4.y)));
  float v2 = x4.z * sc * w4.z * (z4.z / (1.f + __expf(-z4.z)));
  float v3 = x4.w * sc * w4.w * (z4.w / (1.f + __expf(-z4.w)));
  out4.x = (unsigned short)f2bf(v0);
  out4.y = (unsigned short)f2bf(v1);
  out4.z = (unsigned short)f2bf(v2);
  out4.w = (unsigned short)f2bf(v3);
  *(ushort4*)&on[((size_t)bt * 32 + hv) * 64 + d] = out4;
}

// ---------------- launch ----------------
extern "C" void kernel_launch(void* const* d_in, const int* in_sizes, int n_in,
                              void* d_out, int out_size, void* d_ws, size_t ws_size,
                              hipStream_t stream) {
  const float* hidden = (const float*)d_in[0];
  const float* W_qkvz = (const float*)d_in[1];
  const float* W_ba = (const float*)d_in[2];
  const float* conv_w = (const float*)d_in[3];
  const float* dt_bias = (const float*)d_in[4];
  const float* A_log = (const float*)d_in[5];
  const float* norm_w = (const float*)d_in[6];
  const float* W_out = (const float*)d_in[7];
  float* out = (float*)d_out;

  char* ws = (char*)d_ws;
  short* A_bf = (short*)(ws + 0);                // 16,777,216 (dead after GEMM1)
  float* Hbuf = (float*)(ws + 0);                //   reused: H [1024][64][64]
  short* Wt1 = (short*)(ws + 16777216);          // 42,991,616  [5248][4096] (pad)
  short* Wt2 = (short*)(ws + 59768832);          // 16,777,216  [4096][2048]
  float* qkvz = (float*)(ws + 76546048);         // 42,467,328  [2048][5184]
  float* mix = (float*)(ws + 119013376);         // 25,165,824  [2048][3072]
  float* gbuf = (float*)(ws + 144179200);        //    262,144  [2048][32]
  float* beta = (float*)(ws + 144441344);        //    262,144
  float* o = (float*)(ws + 144703488);           // 16,777,216  [256][1024][16]
  short* on = (short*)(ws + 161480704);          //  8,388,608  [2048][2048]
  float* Wbuf = (float*)(ws + 169869312);        // 16,777,216  W -> G (in place)
  float* Pbuf = (float*)(ws + 186646528);        // 16,777,216  P -> KR (in place)
  float* Rbuf = (float*)(ws + 203423744);        // 16,777,216  R -> OR (in place)
  float* cbuf = (float*)(ws + 220200960);        //    262,144  [1024][64]

  // merged prep: to_bf16 (8192) + transpose_w1 (20992) + transpose_w2 (8192)
  prep_kernel<<<37376, 256, 0, stream>>>(hidden, W_qkvz, W_ba, W_out, A_bf, Wt1, Wt2);
  // GEMM1: 16x41 = 656 blocks (r6 config, measured best of the family)
  gemm128p<true><<<656, 256, 0, stream>>>(A_bf, Wt1, qkvz, 5184, 4096, 16);
  conv_kernel<<<2048, 256, 0, stream>>>(qkvz, conv_w, dt_bias, A_log, mix, gbuf, beta);
  precompute_kernel<<<1024, 256, 0, stream>>>(mix, gbuf, beta, Wbuf, Pbuf, Rbuf, cbuf);
  precompute2_kernel<<<1024, 256, 0, stream>>>(mix, cbuf, Wbuf, Pbuf, Rbuf, Hbuf);
  chunk_scan_kernel<<<256, 512, 0, stream>>>(Wbuf, Hbuf, Rbuf, Pbuf, cbuf, o);
  rms_gate_kernel<<<4096, 256, 0, stream>>>(o, qkvz, norm_w, on);
  // GEMM2: 16x32 = 512 blocks, all co-resident at 3/CU.
  gemm128p<false><<<512, 256, 0, stream>>>(on, Wt2, out, 4096, 2048, 16);
}